// Round 5
// baseline (235.035 us; speedup 1.0000x reference)
//
#include <hip/hip_runtime.h>
#include <hip/hip_bf16.h>
#include <stdint.h>

#define N_ROWS 512
#define D_DIM  512
#define C_CLS  100000
#define C_PAD  100096           // 782*128

#define SCALE_F    64.0f
#define EPS_F      1e-7f
#define COS_M_F    0.8775825618903728f
#define SIN_M_F    0.4794255386042030f
#define THRESH_F  -0.8775825618903728f
#define MM_F       0.2397127693021015f

#define NB 782          // ceil(100000/128)
#define NWG 1564        // 4 mb * 391 nb-groups (T=2 nb per block)

// ---- ws layout (bytes) ----
#define XN_OFF     0                          // bf16 bits [512][512]
#define XNORM_OFF  (XN_OFF + 512*512*2)       // f32 [512]
#define WNORM_OFF  (XNORM_OFF + 2048)         // f32 [100096]
#define TL_OFF     (WNORM_OFF + 100096*4)     // f32 [512]
#define CTM_OFF    (TL_OFF + 2048)            // f32 [512]
#define FTL_OFF    (CTM_OFF + 2048)           // f32 [512]
#define TNEW_OFF   (FTL_OFF + 2048)           // f32 [1] (padded)
#define PMAX_OFF   (TNEW_OFF + 256)           // f32 [512][NB]
#define PSUM_OFF   (PMAX_OFF + 512*NB*4)      // f32 [512][NB]
#define LOSSI_OFF  (PSUM_OFF + 512*NB*4)      // f32 [512]
#define WNBF_OFF   (LOSSI_OFF + 2048)         // bf16 bits [100096][512] (fast path only)
#define WS_NEED_FAST ((size_t)WNBF_OFF + (size_t)C_PAD*512*2)

typedef __attribute__((ext_vector_type(8))) short bf16x8;
typedef __attribute__((ext_vector_type(4))) float f32x4;

#define GLOAD_LDS16(gp, lp) \
    __builtin_amdgcn_global_load_lds((const __attribute__((address_space(1))) void*)(gp), \
                                     (__attribute__((address_space(3))) void*)(lp), 16, 0, 0)

__device__ inline unsigned short f2bf(float f) {
    union { float f; unsigned int u; } a; a.f = f;
    unsigned int r = (a.u + 0x7FFFu + ((a.u >> 16) & 1u)) >> 16;
    return (unsigned short)r;
}

__device__ inline float wave_sum64(float v) {
    #pragma unroll
    for (int m = 1; m < 64; m <<= 1) v += __shfl_xor(v, m);
    return v;
}

// K1: x row norms + xn bf16.  grid 512 x 64
__global__ void k_xnorm(const float* __restrict__ x,
                        unsigned short* __restrict__ xn,
                        float* __restrict__ xnorm) {
    int row = blockIdx.x;
    int lane = threadIdx.x;
    const float* xr = x + row * D_DIM + lane * 8;
    float4 v0 = *(const float4*)(xr);
    float4 v1 = *(const float4*)(xr + 4);
    float s = v0.x*v0.x + v0.y*v0.y + v0.z*v0.z + v0.w*v0.w
            + v1.x*v1.x + v1.y*v1.y + v1.z*v1.z + v1.w*v1.w;
    s = wave_sum64(s);
    float nrm = sqrtf(s);
    if (lane == 0) xnorm[row] = nrm;
    float inv = 1.0f / nrm;
    union { unsigned short h[8]; uint4 q; } u;
    u.h[0]=f2bf(v0.x*inv); u.h[1]=f2bf(v0.y*inv); u.h[2]=f2bf(v0.z*inv); u.h[3]=f2bf(v0.w*inv);
    u.h[4]=f2bf(v1.x*inv); u.h[5]=f2bf(v1.y*inv); u.h[6]=f2bf(v1.z*inv); u.h[7]=f2bf(v1.w*inv);
    *(uint4*)(xn + row * D_DIM + lane * 8) = u.q;
}

// K2 (fast): weight row norms + normalized bf16 W (pad rows zeroed).
// grid 25024 x 256 (wave per row)
__global__ void k_wnorm_bf16(const float* __restrict__ w, float* __restrict__ wnorm,
                             unsigned short* __restrict__ wnb) {
    int row = blockIdx.x * 4 + (threadIdx.x >> 6);
    int lane = threadIdx.x & 63;
    if (row < C_CLS) {
        const float* wr = w + (size_t)row * D_DIM + lane * 8;
        float4 v0 = *(const float4*)(wr);
        float4 v1 = *(const float4*)(wr + 4);
        float s = v0.x*v0.x + v0.y*v0.y + v0.z*v0.z + v0.w*v0.w
                + v1.x*v1.x + v1.y*v1.y + v1.z*v1.z + v1.w*v1.w;
        s = wave_sum64(s);
        float nrm = sqrtf(s);
        if (lane == 0) wnorm[row] = nrm;
        float inv = 1.0f / nrm;
        union { unsigned short h[8]; uint4 q; } u;
        u.h[0]=f2bf(v0.x*inv); u.h[1]=f2bf(v0.y*inv); u.h[2]=f2bf(v0.z*inv); u.h[3]=f2bf(v0.w*inv);
        u.h[4]=f2bf(v1.x*inv); u.h[5]=f2bf(v1.y*inv); u.h[6]=f2bf(v1.z*inv); u.h[7]=f2bf(v1.w*inv);
        *(uint4*)(wnb + (size_t)row * D_DIM + lane * 8) = u.q;
    } else {
        uint4 z = {0u, 0u, 0u, 0u};
        *(uint4*)(wnb + (size_t)row * D_DIM + lane * 8) = z;
    }
}

// K2 (fallback): weight row norms only.  grid 25000 x 256
__global__ void k_wnorm(const float* __restrict__ w, float* __restrict__ wnorm) {
    int row = blockIdx.x * 4 + (threadIdx.x >> 6);
    int lane = threadIdx.x & 63;
    const float* wr = w + (size_t)row * D_DIM + lane * 8;
    float4 v0 = *(const float4*)(wr);
    float4 v1 = *(const float4*)(wr + 4);
    float s = v0.x*v0.x + v0.y*v0.y + v0.z*v0.z + v0.w*v0.w
            + v1.x*v1.x + v1.y*v1.y + v1.z*v1.z + v1.w*v1.w;
    s = wave_sum64(s);
    if (lane == 0) wnorm[row] = sqrtf(s);
}

// K3: per-row target logit + margin terms (exact f32).  grid 512 x 64
__global__ void k_tlogit(const float* __restrict__ x, const float* __restrict__ w,
                         const float* __restrict__ xnorm, const float* __restrict__ wnorm,
                         const int* __restrict__ target,
                         float* __restrict__ tl, float* __restrict__ ctm,
                         float* __restrict__ ftl) {
    int row = blockIdx.x;
    int lane = threadIdx.x;
    int tgt = target[row];
    const float* xr = x + row * D_DIM + lane * 8;
    const float* wr = w + (size_t)tgt * D_DIM + lane * 8;
    float4 a0 = *(const float4*)(xr),     a1 = *(const float4*)(xr + 4);
    float4 b0 = *(const float4*)(wr),     b1 = *(const float4*)(wr + 4);
    float s = a0.x*b0.x + a0.y*b0.y + a0.z*b0.z + a0.w*b0.w
            + a1.x*b1.x + a1.y*b1.y + a1.z*b1.z + a1.w*b1.w;
    s = wave_sum64(s);
    if (lane == 0) {
        float c = s / (xnorm[row] * wnorm[tgt]);
        c = fminf(fmaxf(c, -1.0f + EPS_F), 1.0f - EPS_F);
        float sn = sqrtf(fmaxf(1.0f - c * c, 0.0f));
        float cm = c * COS_M_F - sn * SIN_M_F;
        tl[row]  = c;
        ctm[row] = cm;
        ftl[row] = (c > THRESH_F) ? cm : (c - MM_F);
    }
}

// K3b: t_new = mean(tl)*0.01 + 0.99*t.  1 x 512
__global__ void k_tnew(const float* __restrict__ tl, const float* __restrict__ t,
                       float* __restrict__ tnew) {
    __shared__ float s[512];
    int tid = threadIdx.x;
    s[tid] = tl[tid];
    __syncthreads();
    for (int off = 256; off > 0; off >>= 1) {
        if (tid < off) s[tid] += s[tid + off];
        __syncthreads();
    }
    if (tid == 0) tnew[0] = (s[0] / 512.0f) * 0.01f + 0.99f * t[0];
}

// ---------------------------------------------------------------------------
// K4 fast: pure-bf16 GEMM, 128x128 tile, BK=32, double-buffered LDS prefetch,
// T=2 nb-tiles per block (32 K-steps, 1 prologue), 35.5 KB LDS -> 4 blocks/CU,
// global_load_lds staging, bijective XCD remap (1564 = 8q+4), fused
// CurricularFace epilogue + per-(row,nb) online (max,sumexp).
// grid 1564 x 256
// ---------------------------------------------------------------------------
__global__ __launch_bounds__(256) void k_gemm_fast(
        const unsigned short* __restrict__ xn,    // bf16 [512][512]
        const unsigned short* __restrict__ wnb,   // bf16 [100096][512], normalized
        const int* __restrict__ target,
        const float* __restrict__ ctm,
        const float* __restrict__ ftl,
        const float* __restrict__ tnew,
        float* __restrict__ pmax, float* __restrict__ psum) {
    __shared__ unsigned short As[2][128 * 32];   // 2 x 8 KB
    __shared__ unsigned short Bs[2][128 * 32];   // 2 x 8 KB
    __shared__ int   tgt_s[128];
    __shared__ float ctm_s[128];
    __shared__ float ftl_s[128];
    __shared__ float redM[2][128];
    __shared__ float redS[2][128];

    // bijective XCD remap (NWG = 1564 = 8*195 + 4): hw assigns XCD = bx%8;
    // give each XCD a contiguous logical range so the 4 mb-siblings and the
    // 2 nb-siblings of a group are co-XCD (B-tile L2 reuse).
    int bx = blockIdx.x;
    int xcd = bx & 7, idx = bx >> 3;
    const int q = NWG >> 3, r = NWG & 7;      // 195, 4
    int logical = (xcd < r) ? xcd * (q + 1) + idx
                            : r * (q + 1) + (xcd - r) * q + idx;
    int g = logical >> 2, mb = logical & 3;    // g in [0,391), mb in [0,4)
    int rowbase = mb * 128;

    int tid = threadIdx.x;
    int lane = tid & 63, wid = tid >> 6;
    int wm = wid >> 1, wn = wid & 1;

    if (tid < 128) {
        int rg = rowbase + tid;
        tgt_s[tid] = target[rg];
        ctm_s[tid] = ctm[rg];
        ftl_s[tid] = ftl[rg];
    }
    float tn = tnew[0];

    const char* Ab = (const char*)xn;     // row stride 1024 B
    const char* Bb = (const char*)wnb;    // row stride 1024 B

    // staging: tile = [128 rows][64 B].  Wave wid owns rows [wid*32, +32)
    // = bytes [wid*2048, +2048), in 2 chunks of 1 KB (64 lanes x 16 B).
    // LDS dest is linear wave-uniform base (+ lane*16 by HW).
    auto stage = [&](int ktn, int colbn, int buf) {
        #pragma unroll
        for (int c = 0; c < 2; ++c) {
            int lo = wid * 2048 + c * 1024;
            int o  = lo + lane * 16;
            int row = o >> 6, kb = o & 63;
            GLOAD_LDS16(Ab + (size_t)(rowbase + row) * 1024 + ktn * 64 + kb,
                        (char*)As[buf] + lo);
            GLOAD_LDS16(Bb + (size_t)(colbn + row) * 1024 + ktn * 64 + kb,
                        (char*)Bs[buf] + lo);
        }
    };

    int fr = lane & 15;
    int kgb = (lane >> 4) * 16;               // k-group byte offset within row

    stage(0, 2 * g * 128, 0);
    __syncthreads();                           // tile 0 staged (vmcnt drained)

    int s = 0;
    for (int t = 0; t < 2; ++t) {
        int colb = (2 * g + t) * 128;

        f32x4 acc[4][4];
        #pragma unroll
        for (int m = 0; m < 4; m++)
            #pragma unroll
            for (int n = 0; n < 4; n++)
                acc[m][n] = (f32x4){0.f, 0.f, 0.f, 0.f};

        #pragma unroll 2
        for (int kt = 0; kt < 16; ++kt, ++s) {
            int cur = s & 1;
            if (kt < 15)      stage(kt + 1, colb, cur ^ 1);   // prefetch
            else if (t == 0)  stage(0, colb + 128, cur ^ 1);  // next nb tile

            const char* Ac = (const char*)As[cur];
            const char* Bc = (const char*)Bs[cur];
            bf16x8 af[4], bfr[4];
            #pragma unroll
            for (int m = 0; m < 4; m++)
                af[m] = *(const bf16x8*)(Ac + (wm*64 + m*16 + fr)*64 + kgb);
            #pragma unroll
            for (int n = 0; n < 4; n++)
                bfr[n] = *(const bf16x8*)(Bc + (wn*64 + n*16 + fr)*64 + kgb);
            #pragma unroll
            for (int m = 0; m < 4; m++)
                #pragma unroll
                for (int n = 0; n < 4; n++)
                    acc[m][n] = __builtin_amdgcn_mfma_f32_16x16x32_bf16(af[m], bfr[n], acc[m][n], 0, 0, 0);
            __syncthreads();   // prefetch landed + buffer handoff
        }

        // ---- fused CurricularFace epilogue + per-row online (max,sumexp) ----
        int cgrp = lane & 15, rgrp = lane >> 4;
        #pragma unroll
        for (int m = 0; m < 4; m++) {
            #pragma unroll
            for (int reg = 0; reg < 4; reg++) {
                int rl = wm * 64 + m * 16 + rgrp * 4 + reg;
                int tr = tgt_s[rl];
                float cm = ctm_s[rl];
                float vv[4];
                bool valid[4];
                #pragma unroll
                for (int n = 0; n < 4; n++) {
                    int cl = wn * 64 + n * 16 + cgrp;
                    int cgl = colb + cl;
                    float c = acc[m][n][reg];
                    c = fminf(fmaxf(c, -1.0f + EPS_F), 1.0f - EPS_F);
                    float v;
                    if (cgl >= C_CLS)      { v = -3.0e38f; valid[n] = false; }
                    else if (cgl == tr)    { v = ftl_s[rl] * SCALE_F; valid[n] = true; }
                    else {
                        v = (c > cm) ? c * (tn + c) : c;
                        v *= SCALE_F;
                        valid[n] = true;
                    }
                    vv[n] = v;
                }
                float mx = fmaxf(fmaxf(vv[0], vv[1]), fmaxf(vv[2], vv[3]));
                #pragma unroll
                for (int msk = 1; msk < 16; msk <<= 1) mx = fmaxf(mx, __shfl_xor(mx, msk));
                float sm = 0.0f;
                #pragma unroll
                for (int n = 0; n < 4; n++) sm += valid[n] ? __expf(vv[n] - mx) : 0.0f;
                #pragma unroll
                for (int msk = 1; msk < 16; msk <<= 1) sm += __shfl_xor(sm, msk);
                if (cgrp == 0) { redM[wn][rl] = mx; redS[wn][rl] = sm; }
            }
        }
        __syncthreads();
        if (tid < 128) {
            float m0 = redM[0][tid], s0 = redS[0][tid];
            float m1 = redM[1][tid], s1 = redS[1][tid];
            float M = fmaxf(m0, m1);
            float S = s0 * __expf(m0 - M) + s1 * __expf(m1 - M);
            size_t odx = (size_t)(rowbase + tid) * NB + (2 * g + t);
            pmax[odx] = M;
            psum[odx] = S;
        }
    }
}

// ---------------------------------------------------------------------------
// K4 fallback (round-2 version): f32 W load + on-the-fly normalize/convert.
// grid NB*4 x 256
// ---------------------------------------------------------------------------
__global__ __launch_bounds__(256) void k_gemm_epi(
        const unsigned short* __restrict__ xn,
        const float* __restrict__ w,
        const float* __restrict__ wnorm,
        const int* __restrict__ target,
        const float* __restrict__ ctm,
        const float* __restrict__ ftl,
        const float* __restrict__ tnew,
        float* __restrict__ pmax, float* __restrict__ psum) {
    __shared__ unsigned short As[128 * 32];
    __shared__ unsigned short Bs[128 * 32];
    __shared__ int   tgt_s[128];
    __shared__ float ctm_s[128];
    __shared__ float ftl_s[128];
    __shared__ float redM[2][128];
    __shared__ float redS[2][128];

    int bx = blockIdx.x;
    int nb = bx >> 2, mb = bx & 3;
    int rowbase = mb * 128, colbase = nb * 128;
    int tid = threadIdx.x;
    int lane = tid & 63, wid = tid >> 6;
    int wm = wid >> 1, wn = wid & 1;

    if (tid < 128) {
        int rg = rowbase + tid;
        tgt_s[tid] = target[rg];
        ctm_s[tid] = ctm[rg];
        ftl_s[tid] = ftl[rg];
    }
    float tn = tnew[0];

    int srow = tid >> 1;
    int skq  = (tid & 1) * 16;
    int cg = colbase + srow;
    float wscale = 0.0f;
    if (cg < C_CLS) wscale = 1.0f / wnorm[cg];

    f32x4 acc[4][4];
    #pragma unroll
    for (int m = 0; m < 4; m++)
        #pragma unroll
        for (int n = 0; n < 4; n++)
            acc[m][n] = (f32x4){0.f, 0.f, 0.f, 0.f};

    for (int kt = 0; kt < D_DIM / 32; ++kt) {
        int k0 = kt * 32;
        __syncthreads();
        {
            const uint4* src = (const uint4*)(xn + (rowbase + srow) * D_DIM + k0 + skq);
            uint4 a0 = src[0], a1 = src[1];
            *(uint4*)(&As[srow * 32 + skq])     = a0;
            *(uint4*)(&As[srow * 32 + skq + 8]) = a1;
        }
        {
            union { unsigned short h[16]; uint4 q[2]; } pk;
            if (cg < C_CLS) {
                const float4* src = (const float4*)(w + (size_t)cg * D_DIM + k0 + skq);
                #pragma unroll
                for (int q = 0; q < 4; q++) {
                    float4 v = src[q];
                    pk.h[q*4+0] = f2bf(v.x * wscale);
                    pk.h[q*4+1] = f2bf(v.y * wscale);
                    pk.h[q*4+2] = f2bf(v.z * wscale);
                    pk.h[q*4+3] = f2bf(v.w * wscale);
                }
            } else {
                #pragma unroll
                for (int j = 0; j < 16; j++) pk.h[j] = 0;
            }
            *(uint4*)(&Bs[srow * 32 + skq])     = pk.q[0];
            *(uint4*)(&Bs[srow * 32 + skq + 8]) = pk.q[1];
        }
        __syncthreads();
        int fr = lane & 15, kg = (lane >> 4) * 8;
        bf16x8 af[4], bfr[4];
        #pragma unroll
        for (int m = 0; m < 4; m++)
            af[m] = *(const bf16x8*)(&As[(wm * 64 + m * 16 + fr) * 32 + kg]);
        #pragma unroll
        for (int n = 0; n < 4; n++)
            bfr[n] = *(const bf16x8*)(&Bs[(wn * 64 + n * 16 + fr) * 32 + kg]);
        #pragma unroll
        for (int m = 0; m < 4; m++)
            #pragma unroll
            for (int n = 0; n < 4; n++)
                acc[m][n] = __builtin_amdgcn_mfma_f32_16x16x32_bf16(af[m], bfr[n], acc[m][n], 0, 0, 0);
    }

    int cgrp = lane & 15, rgrp = lane >> 4;
    #pragma unroll
    for (int m = 0; m < 4; m++) {
        #pragma unroll
        for (int reg = 0; reg < 4; reg++) {
            int rl = wm * 64 + m * 16 + rgrp * 4 + reg;
            int tr = tgt_s[rl];
            float cm = ctm_s[rl];
            float vv[4];
            bool valid[4];
            #pragma unroll
            for (int n = 0; n < 4; n++) {
                int cl = wn * 64 + n * 16 + cgrp;
                int cgl = colbase + cl;
                float c = acc[m][n][reg];
                c = fminf(fmaxf(c, -1.0f + EPS_F), 1.0f - EPS_F);
                float v;
                if (cgl >= C_CLS)      { v = -3.0e38f; valid[n] = false; }
                else if (cgl == tr)    { v = ftl_s[rl] * SCALE_F; valid[n] = true; }
                else {
                    v = (c > cm) ? c * (tn + c) : c;
                    v *= SCALE_F;
                    valid[n] = true;
                }
                vv[n] = v;
            }
            float mx = fmaxf(fmaxf(vv[0], vv[1]), fmaxf(vv[2], vv[3]));
            #pragma unroll
            for (int msk = 1; msk < 16; msk <<= 1) mx = fmaxf(mx, __shfl_xor(mx, msk));
            float sm = 0.0f;
            #pragma unroll
            for (int n = 0; n < 4; n++) sm += valid[n] ? __expf(vv[n] - mx) : 0.0f;
            #pragma unroll
            for (int msk = 1; msk < 16; msk <<= 1) sm += __shfl_xor(sm, msk);
            if (cgrp == 0) { redM[wn][rl] = mx; redS[wn][rl] = sm; }
        }
    }
    __syncthreads();
    if (tid < 128) {
        float m0 = redM[0][tid], s0 = redS[0][tid];
        float m1 = redM[1][tid], s1 = redS[1][tid];
        float M = fmaxf(m0, m1);
        float S = s0 * __expf(m0 - M) + s1 * __expf(m1 - M);
        size_t idx = (size_t)(rowbase + tid) * NB + nb;
        pmax[idx] = M;
        psum[idx] = S;
    }
}

// K5: per-row logsumexp over NB partials -> loss_i.  grid 512 x 256
__global__ void k_rowlse(const float* __restrict__ pmax, const float* __restrict__ psum,
                         const float* __restrict__ ftl, float* __restrict__ lossi) {
    int row = blockIdx.x, tid = threadIdx.x;
    float M = -3.0e38f, S = 0.0f;
    for (int nb = tid; nb < NB; nb += 256) {
        float m = pmax[(size_t)row * NB + nb];
        float s = psum[(size_t)row * NB + nb];
        float nm = fmaxf(M, m);
        S = S * __expf(M - nm) + s * __expf(m - nm);
        M = nm;
    }
    __shared__ float sM[256], sS[256];
    sM[tid] = M; sS[tid] = S;
    __syncthreads();
    for (int off = 128; off > 0; off >>= 1) {
        if (tid < off) {
            float m2 = sM[tid + off], s2 = sS[tid + off];
            float nm = fmaxf(sM[tid], m2);
            sS[tid] = sS[tid] * __expf(sM[tid] - nm) + s2 * __expf(m2 - nm);
            sM[tid] = nm;
        }
        __syncthreads();
    }
    if (tid == 0) lossi[row] = logf(sS[0]) + sM[0] - SCALE_F * ftl[row];
}

// K6: loss = mean(loss_i).  1 x 512
__global__ void k_final(const float* __restrict__ lossi, float* __restrict__ out) {
    __shared__ float s[512];
    int tid = threadIdx.x;
    s[tid] = lossi[tid];
    __syncthreads();
    for (int off = 256; off > 0; off >>= 1) {
        if (tid < off) s[tid] += s[tid + off];
        __syncthreads();
    }
    if (tid == 0) out[0] = s[0] / 512.0f;
}

extern "C" void kernel_launch(void* const* d_in, const int* in_sizes, int n_in,
                              void* d_out, int out_size, void* d_ws, size_t ws_size,
                              hipStream_t stream) {
    const float* x      = (const float*)d_in[0];
    const float* w      = (const float*)d_in[1];
    const float* t      = (const float*)d_in[2];
    const int*   target = (const int*)d_in[3];

    char* ws = (char*)d_ws;
    unsigned short* xn  = (unsigned short*)(ws + XN_OFF);
    float* xnorm = (float*)(ws + XNORM_OFF);
    float* wnorm = (float*)(ws + WNORM_OFF);
    float* tl    = (float*)(ws + TL_OFF);
    float* ctm   = (float*)(ws + CTM_OFF);
    float* ftl   = (float*)(ws + FTL_OFF);
    float* tnew  = (float*)(ws + TNEW_OFF);
    float* pmax  = (float*)(ws + PMAX_OFF);
    float* psum  = (float*)(ws + PSUM_OFF);
    float* lossi = (float*)(ws + LOSSI_OFF);
    unsigned short* wnb = (unsigned short*)(ws + WNBF_OFF);
    float* out   = (float*)d_out;

    bool fast = (ws_size >= WS_NEED_FAST);

    k_xnorm<<<dim3(N_ROWS), dim3(64), 0, stream>>>(x, xn, xnorm);
    if (fast) {
        k_wnorm_bf16<<<dim3(C_PAD / 4), dim3(256), 0, stream>>>(w, wnorm, wnb);
    } else {
        k_wnorm<<<dim3(C_CLS / 4), dim3(256), 0, stream>>>(w, wnorm);
    }
    k_tlogit<<<dim3(N_ROWS), dim3(64), 0, stream>>>(x, w, xnorm, wnorm, target, tl, ctm, ftl);
    k_tnew<<<dim3(1), dim3(512), 0, stream>>>(tl, t, tnew);
    if (fast) {
        k_gemm_fast<<<dim3(NWG), dim3(256), 0, stream>>>(xn, wnb, target, ctm, ftl, tnew, pmax, psum);
    } else {
        k_gemm_epi<<<dim3(NB * 4), dim3(256), 0, stream>>>(xn, w, wnorm, target, ctm, ftl, tnew, pmax, psum);
    }
    k_rowlse<<<dim3(N_ROWS), dim3(256), 0, stream>>>(pmax, psum, ftl, lossi);
    k_final<<<dim3(1), dim3(512), 0, stream>>>(lossi, out);
}

// Round 6
// 185.481 us; speedup vs baseline: 1.2672x; 1.2672x over previous
//
#include <hip/hip_runtime.h>
#include <hip/hip_bf16.h>
#include <stdint.h>

#define N_ROWS 512
#define D_DIM  512
#define C_CLS  100000
#define C_PAD  100096           // 391*256

#define SCALE_F    64.0f
#define EPS_F      1e-7f
#define COS_M_F    0.8775825618903728f
#define SIN_M_F    0.4794255386042030f
#define THRESH_F  -0.8775825618903728f
#define MM_F       0.2397127693021015f

#define NB 782          // fallback col-blocks of 128
#define NG 391          // fast-path col-groups of 256

// ---- ws layout (bytes) ----
#define XN_OFF     0                          // bf16 bits [512][512]
#define XNORM_OFF  (XN_OFF + 512*512*2)       // f32 [512]
#define WNORM_OFF  (XNORM_OFF + 2048)         // f32 [100096]
#define TL_OFF     (WNORM_OFF + 100096*4)     // f32 [512]
#define CTM_OFF    (TL_OFF + 2048)            // f32 [512]
#define FTL_OFF    (CTM_OFF + 2048)           // f32 [512]
#define TNEW_OFF   (FTL_OFF + 2048)           // f32 [1] (padded)
#define PMAX_OFF   (TNEW_OFF + 256)           // f32 [512][NB] (>= [512][NG])
#define PSUM_OFF   (PMAX_OFF + 512*NB*4)      // f32 [512][NB]
#define LOSSI_OFF  (PSUM_OFF + 512*NB*4)      // f32 [512]
#define WNBF_OFF   (LOSSI_OFF + 2048)         // bf16 bits [100096][512] (fast path)
#define WS_NEED_FAST ((size_t)WNBF_OFF + (size_t)C_PAD*512*2)

typedef __attribute__((ext_vector_type(8))) short bf16x8;
typedef __attribute__((ext_vector_type(4))) float f32x4;

#define GLOAD_LDS16(gp, lp) \
    __builtin_amdgcn_global_load_lds((const __attribute__((address_space(1))) void*)(gp), \
                                     (__attribute__((address_space(3))) void*)(lp), 16, 0, 0)

__device__ inline unsigned short f2bf(float f) {
    union { float f; unsigned int u; } a; a.f = f;
    unsigned int r = (a.u + 0x7FFFu + ((a.u >> 16) & 1u)) >> 16;
    return (unsigned short)r;
}

__device__ inline float wave_sum64(float v) {
    #pragma unroll
    for (int m = 1; m < 64; m <<= 1) v += __shfl_xor(v, m);
    return v;
}

// K1: x row norms + xn bf16.  grid 512 x 64
__global__ void k_xnorm(const float* __restrict__ x,
                        unsigned short* __restrict__ xn,
                        float* __restrict__ xnorm) {
    int row = blockIdx.x;
    int lane = threadIdx.x;
    const float* xr = x + row * D_DIM + lane * 8;
    float4 v0 = *(const float4*)(xr);
    float4 v1 = *(const float4*)(xr + 4);
    float s = v0.x*v0.x + v0.y*v0.y + v0.z*v0.z + v0.w*v0.w
            + v1.x*v1.x + v1.y*v1.y + v1.z*v1.z + v1.w*v1.w;
    s = wave_sum64(s);
    float nrm = sqrtf(s);
    if (lane == 0) xnorm[row] = nrm;
    float inv = 1.0f / nrm;
    union { unsigned short h[8]; uint4 q; } u;
    u.h[0]=f2bf(v0.x*inv); u.h[1]=f2bf(v0.y*inv); u.h[2]=f2bf(v0.z*inv); u.h[3]=f2bf(v0.w*inv);
    u.h[4]=f2bf(v1.x*inv); u.h[5]=f2bf(v1.y*inv); u.h[6]=f2bf(v1.z*inv); u.h[7]=f2bf(v1.w*inv);
    *(uint4*)(xn + row * D_DIM + lane * 8) = u.q;
}

// K2 (fast): weight row norms + normalized bf16 W (pad rows zeroed).
// grid 25024 x 256 (wave per row)
__global__ void k_wnorm_bf16(const float* __restrict__ w, float* __restrict__ wnorm,
                             unsigned short* __restrict__ wnb) {
    int row = blockIdx.x * 4 + (threadIdx.x >> 6);
    int lane = threadIdx.x & 63;
    if (row < C_CLS) {
        const float* wr = w + (size_t)row * D_DIM + lane * 8;
        float4 v0 = *(const float4*)(wr);
        float4 v1 = *(const float4*)(wr + 4);
        float s = v0.x*v0.x + v0.y*v0.y + v0.z*v0.z + v0.w*v0.w
                + v1.x*v1.x + v1.y*v1.y + v1.z*v1.z + v1.w*v1.w;
        s = wave_sum64(s);
        float nrm = sqrtf(s);
        if (lane == 0) wnorm[row] = nrm;
        float inv = 1.0f / nrm;
        union { unsigned short h[8]; uint4 q; } u;
        u.h[0]=f2bf(v0.x*inv); u.h[1]=f2bf(v0.y*inv); u.h[2]=f2bf(v0.z*inv); u.h[3]=f2bf(v0.w*inv);
        u.h[4]=f2bf(v1.x*inv); u.h[5]=f2bf(v1.y*inv); u.h[6]=f2bf(v1.z*inv); u.h[7]=f2bf(v1.w*inv);
        *(uint4*)(wnb + (size_t)row * D_DIM + lane * 8) = u.q;
    } else {
        uint4 z = {0u, 0u, 0u, 0u};
        *(uint4*)(wnb + (size_t)row * D_DIM + lane * 8) = z;
    }
}

// K2 (fallback): weight row norms only.  grid 25000 x 256
__global__ void k_wnorm(const float* __restrict__ w, float* __restrict__ wnorm) {
    int row = blockIdx.x * 4 + (threadIdx.x >> 6);
    int lane = threadIdx.x & 63;
    const float* wr = w + (size_t)row * D_DIM + lane * 8;
    float4 v0 = *(const float4*)(wr);
    float4 v1 = *(const float4*)(wr + 4);
    float s = v0.x*v0.x + v0.y*v0.y + v0.z*v0.z + v0.w*v0.w
            + v1.x*v1.x + v1.y*v1.y + v1.z*v1.z + v1.w*v1.w;
    s = wave_sum64(s);
    if (lane == 0) wnorm[row] = sqrtf(s);
}

// K3: per-row target logit + margin terms (exact f32).  grid 512 x 64
__global__ void k_tlogit(const float* __restrict__ x, const float* __restrict__ w,
                         const float* __restrict__ xnorm, const float* __restrict__ wnorm,
                         const int* __restrict__ target,
                         float* __restrict__ tl, float* __restrict__ ctm,
                         float* __restrict__ ftl) {
    int row = blockIdx.x;
    int lane = threadIdx.x;
    int tgt = target[row];
    const float* xr = x + row * D_DIM + lane * 8;
    const float* wr = w + (size_t)tgt * D_DIM + lane * 8;
    float4 a0 = *(const float4*)(xr),     a1 = *(const float4*)(xr + 4);
    float4 b0 = *(const float4*)(wr),     b1 = *(const float4*)(wr + 4);
    float s = a0.x*b0.x + a0.y*b0.y + a0.z*b0.z + a0.w*b0.w
            + a1.x*b1.x + a1.y*b1.y + a1.z*b1.z + a1.w*b1.w;
    s = wave_sum64(s);
    if (lane == 0) {
        float c = s / (xnorm[row] * wnorm[tgt]);
        c = fminf(fmaxf(c, -1.0f + EPS_F), 1.0f - EPS_F);
        float sn = sqrtf(fmaxf(1.0f - c * c, 0.0f));
        float cm = c * COS_M_F - sn * SIN_M_F;
        tl[row]  = c;
        ctm[row] = cm;
        ftl[row] = (c > THRESH_F) ? cm : (c - MM_F);
    }
}

// K3b: t_new = mean(tl)*0.01 + 0.99*t.  1 x 512
__global__ void k_tnew(const float* __restrict__ tl, const float* __restrict__ t,
                       float* __restrict__ tnew) {
    __shared__ float s[512];
    int tid = threadIdx.x;
    s[tid] = tl[tid];
    __syncthreads();
    for (int off = 256; off > 0; off >>= 1) {
        if (tid < off) s[tid] += s[tid + off];
        __syncthreads();
    }
    if (tid == 0) tnew[0] = (s[0] / 512.0f) * 0.01f + 0.99f * t[0];
}

// ---------------------------------------------------------------------------
// K4 fast: barrier-free streaming GEMM.
//  - block = 4 waves, 64 A-rows (mb in [0,8)), 256 classes (ng in [0,391)).
//  - A staged ONCE to LDS in frag-major layout [kk][m][1KB] (conflict-free
//    ds_read_b128 by construction); ONE __syncthreads total before compute.
//  - each wave owns a 64x64 output chunk: B frags stream global->VGPR with
//    depth-2 register double-buffer; A frags ds_read 1 iter ahead.
//  - full-K accumulate, then two-pass register epilogue (transform, row-max
//    via 16-lane shuffles, exp-sum), LDS combine across 4 waves.
// grid 3128 x 256
// ---------------------------------------------------------------------------
__global__ __launch_bounds__(256) void k_gemm_stream(
        const unsigned short* __restrict__ xn,    // bf16 [512][512]
        const unsigned short* __restrict__ wnb,   // bf16 [100096][512], normalized
        const int* __restrict__ target,
        const float* __restrict__ ctm,
        const float* __restrict__ ftl,
        const float* __restrict__ tnew,
        float* __restrict__ pmax, float* __restrict__ psum) {
    __shared__ unsigned short As[16 * 4 * 512];   // 64 KB, [kk][m][1KB frag]
    __shared__ int   tgt_s[64];
    __shared__ float ctm_s[64];
    __shared__ float ftl_s[64];
    __shared__ float redM[4][64];
    __shared__ float redS[4][64];

    // XCD remap: 3128 = 8*391; logical = ng*8 + mb so all 8 mb-siblings of an
    // ng (sharing the same 256 B-rows) land on one XCD, contiguous ng windows.
    int bx = blockIdx.x;
    int logical = (bx & 7) * 391 + (bx >> 3);
    int ng = logical >> 3, mb = logical & 7;
    int rowbase = mb * 64;

    int tid = threadIdx.x;
    int lane = tid & 63, wid = tid >> 6;
    int fr = lane & 15, rgrp = lane >> 4;
    int cb = ng * 256 + wid * 64;              // this wave's first class

    if (tid < 64) {
        int rg = rowbase + tid;
        tgt_s[tid] = target[rg];
        ctm_s[tid] = ctm[rg];
        ftl_s[tid] = ftl[rg];
    }

    const char* Ab = (const char*)xn;     // row stride 1024 B
    const char* Bb = (const char*)wnb;    // row stride 1024 B

    // ---- B lane base pointers (per n-tile j): row = cb + j*16 + fr ----
    const char* bptr[4];
    #pragma unroll
    for (int j = 0; j < 4; j++)
        bptr[j] = Bb + (size_t)(cb + j * 16 + fr) * 1024 + rgrp * 16;

    // ---- issue B preloads for kk=0,1 (overlaps A staging) ----
    bf16x8 bv[2][4];
    #pragma unroll
    for (int j = 0; j < 4; j++) bv[0][j] = *(const bf16x8*)(bptr[j]);
    #pragma unroll
    for (int j = 0; j < 4; j++) bv[1][j] = *(const bf16x8*)(bptr[j] + 64);

    // ---- stage A: 64 chunks of 1 KB, chunk c=(kk,m): frag-major ----
    // staging lane l writes 16B for (frag-row l>>2, k-slot l&3):
    //   src = A[rowbase + m*16 + (l>>2)] bytes [kk*64 + (l&3)*16, +16)
    //   dst = As + c*1024 + l*16  (linear, HW adds lane*16)
    {
        int asrow = lane >> 2, askb = (lane & 3) * 16;
        #pragma unroll
        for (int cc = 0; cc < 16; ++cc) {
            int c = wid * 16 + cc;
            int kk = c >> 2, m = c & 3;
            GLOAD_LDS16(Ab + (size_t)(rowbase + m * 16 + asrow) * 1024 + kk * 64 + askb,
                        (char*)As + c * 1024);
        }
    }
    __syncthreads();                           // the ONLY pre-compute barrier

    float tn = tnew[0];

    // reader lane offset within a frag: (fr)*64 + rgrp*16
    int albase = fr * 64 + rgrp * 16;

    f32x4 acc[4][4];                           // [m][j]
    #pragma unroll
    for (int m = 0; m < 4; m++)
        #pragma unroll
        for (int j = 0; j < 4; j++)
            acc[m][j] = (f32x4){0.f, 0.f, 0.f, 0.f};

    bf16x8 af[2][4];
    #pragma unroll
    for (int m = 0; m < 4; m++)
        af[0][m] = *(const bf16x8*)((const char*)As + m * 1024 + albase);

    #pragma unroll
    for (int kk = 0; kk < 16; ++kk) {
        int cur = kk & 1;
        if (kk < 15) {
            #pragma unroll
            for (int m = 0; m < 4; m++)
                af[cur ^ 1][m] = *(const bf16x8*)((const char*)As
                                 + (kk + 1) * 4096 + m * 1024 + albase);
        }
        #pragma unroll
        for (int m = 0; m < 4; m++)
            #pragma unroll
            for (int j = 0; j < 4; j++)
                acc[m][j] = __builtin_amdgcn_mfma_f32_16x16x32_bf16(
                                af[cur][m], bv[cur][j], acc[m][j], 0, 0, 0);
        if (kk < 14) {
            #pragma unroll
            for (int j = 0; j < 4; j++)
                bv[cur][j] = *(const bf16x8*)(bptr[j] + (kk + 2) * 64);
        }
    }

    // ---- epilogue: transform in place, then row (max, sumexp) ----
    // C/D layout: col = cb + j*16 + fr, row = m*16 + rgrp*4 + reg.
    #pragma unroll
    for (int m = 0; m < 4; m++) {
        #pragma unroll
        for (int reg = 0; reg < 4; reg++) {
            int rl = m * 16 + rgrp * 4 + reg;
            int tr = tgt_s[rl];
            float cm = ctm_s[rl];
            float ft = ftl_s[rl];
            #pragma unroll
            for (int j = 0; j < 4; j++) {
                int col = cb + j * 16 + fr;
                float c = acc[m][j][reg];
                c = fminf(fmaxf(c, -1.0f + EPS_F), 1.0f - EPS_F);
                float v = (c > cm) ? c * (tn + c) : c;
                v *= SCALE_F;
                v = (col == tr) ? ft * SCALE_F : v;
                v = (col < C_CLS) ? v : -3.0e38f;
                acc[m][j][reg] = v;
            }
        }
    }
    // per-(m,reg) row max over j + 16-lane group, then sumexp
    #pragma unroll
    for (int m = 0; m < 4; m++) {
        #pragma unroll
        for (int reg = 0; reg < 4; reg++) {
            float mx = fmaxf(fmaxf(acc[m][0][reg], acc[m][1][reg]),
                             fmaxf(acc[m][2][reg], acc[m][3][reg]));
            #pragma unroll
            for (int msk = 1; msk < 16; msk <<= 1) mx = fmaxf(mx, __shfl_xor(mx, msk));
            float sm = __expf(acc[m][0][reg] - mx) + __expf(acc[m][1][reg] - mx)
                     + __expf(acc[m][2][reg] - mx) + __expf(acc[m][3][reg] - mx);
            #pragma unroll
            for (int msk = 1; msk < 16; msk <<= 1) sm += __shfl_xor(sm, msk);
            if (fr == 0) {
                int rl = m * 16 + rgrp * 4 + reg;
                redM[wid][rl] = mx;
                redS[wid][rl] = sm;
            }
        }
    }
    __syncthreads();
    if (tid < 64) {
        float M = fmaxf(fmaxf(redM[0][tid], redM[1][tid]),
                        fmaxf(redM[2][tid], redM[3][tid]));
        float S = redS[0][tid] * __expf(redM[0][tid] - M)
                + redS[1][tid] * __expf(redM[1][tid] - M)
                + redS[2][tid] * __expf(redM[2][tid] - M)
                + redS[3][tid] * __expf(redM[3][tid] - M);
        size_t odx = (size_t)(rowbase + tid) * NG + ng;
        pmax[odx] = M;
        psum[odx] = S;
    }
}

// ---------------------------------------------------------------------------
// K4 fallback (round-2 version): f32 W load + on-the-fly normalize/convert.
// grid NB*4 x 256, partials [512][NB]
// ---------------------------------------------------------------------------
__global__ __launch_bounds__(256) void k_gemm_epi(
        const unsigned short* __restrict__ xn,
        const float* __restrict__ w,
        const float* __restrict__ wnorm,
        const int* __restrict__ target,
        const float* __restrict__ ctm,
        const float* __restrict__ ftl,
        const float* __restrict__ tnew,
        float* __restrict__ pmax, float* __restrict__ psum) {
    __shared__ unsigned short As[128 * 32];
    __shared__ unsigned short Bs[128 * 32];
    __shared__ int   tgt_s[128];
    __shared__ float ctm_s[128];
    __shared__ float ftl_s[128];
    __shared__ float redM[2][128];
    __shared__ float redS[2][128];

    int bx = blockIdx.x;
    int nb = bx >> 2, mb = bx & 3;
    int rowbase = mb * 128, colbase = nb * 128;
    int tid = threadIdx.x;
    int lane = tid & 63, wid = tid >> 6;
    int wm = wid >> 1, wn = wid & 1;

    if (tid < 128) {
        int rg = rowbase + tid;
        tgt_s[tid] = target[rg];
        ctm_s[tid] = ctm[rg];
        ftl_s[tid] = ftl[rg];
    }
    float tn = tnew[0];

    int srow = tid >> 1;
    int skq  = (tid & 1) * 16;
    int cg = colbase + srow;
    float wscale = 0.0f;
    if (cg < C_CLS) wscale = 1.0f / wnorm[cg];

    f32x4 acc[4][4];
    #pragma unroll
    for (int m = 0; m < 4; m++)
        #pragma unroll
        for (int n = 0; n < 4; n++)
            acc[m][n] = (f32x4){0.f, 0.f, 0.f, 0.f};

    for (int kt = 0; kt < D_DIM / 32; ++kt) {
        int k0 = kt * 32;
        __syncthreads();
        {
            const uint4* src = (const uint4*)(xn + (rowbase + srow) * D_DIM + k0 + skq);
            uint4 a0 = src[0], a1 = src[1];
            *(uint4*)(&As[srow * 32 + skq])     = a0;
            *(uint4*)(&As[srow * 32 + skq + 8]) = a1;
        }
        {
            union { unsigned short h[16]; uint4 q[2]; } pk;
            if (cg < C_CLS) {
                const float4* src = (const float4*)(w + (size_t)cg * D_DIM + k0 + skq);
                #pragma unroll
                for (int q = 0; q < 4; q++) {
                    float4 v = src[q];
                    pk.h[q*4+0] = f2bf(v.x * wscale);
                    pk.h[q*4+1] = f2bf(v.y * wscale);
                    pk.h[q*4+2] = f2bf(v.z * wscale);
                    pk.h[q*4+3] = f2bf(v.w * wscale);
                }
            } else {
                #pragma unroll
                for (int j = 0; j < 16; j++) pk.h[j] = 0;
            }
            *(uint4*)(&Bs[srow * 32 + skq])     = pk.q[0];
            *(uint4*)(&Bs[srow * 32 + skq + 8]) = pk.q[1];
        }
        __syncthreads();
        int fr = lane & 15, kg = (lane >> 4) * 8;
        bf16x8 af[4], bfr[4];
        #pragma unroll
        for (int m = 0; m < 4; m++)
            af[m] = *(const bf16x8*)(&As[(wm * 64 + m * 16 + fr) * 32 + kg]);
        #pragma unroll
        for (int n = 0; n < 4; n++)
            bfr[n] = *(const bf16x8*)(&Bs[(wn * 64 + n * 16 + fr) * 32 + kg]);
        #pragma unroll
        for (int m = 0; m < 4; m++)
            #pragma unroll
            for (int n = 0; n < 4; n++)
                acc[m][n] = __builtin_amdgcn_mfma_f32_16x16x32_bf16(af[m], bfr[n], acc[m][n], 0, 0, 0);
    }

    int cgrp = lane & 15, rgrp = lane >> 4;
    #pragma unroll
    for (int m = 0; m < 4; m++) {
        #pragma unroll
        for (int reg = 0; reg < 4; reg++) {
            int rl = wm * 64 + m * 16 + rgrp * 4 + reg;
            int tr = tgt_s[rl];
            float cm = ctm_s[rl];
            float vv[4];
            bool valid[4];
            #pragma unroll
            for (int n = 0; n < 4; n++) {
                int cl = wn * 64 + n * 16 + cgrp;
                int cgl = colbase + cl;
                float c = acc[m][n][reg];
                c = fminf(fmaxf(c, -1.0f + EPS_F), 1.0f - EPS_F);
                float v;
                if (cgl >= C_CLS)      { v = -3.0e38f; valid[n] = false; }
                else if (cgl == tr)    { v = ftl_s[rl] * SCALE_F; valid[n] = true; }
                else {
                    v = (c > cm) ? c * (tn + c) : c;
                    v *= SCALE_F;
                    valid[n] = true;
                }
                vv[n] = v;
            }
            float mx = fmaxf(fmaxf(vv[0], vv[1]), fmaxf(vv[2], vv[3]));
            #pragma unroll
            for (int msk = 1; msk < 16; msk <<= 1) mx = fmaxf(mx, __shfl_xor(mx, msk));
            float sm = 0.0f;
            #pragma unroll
            for (int n = 0; n < 4; n++) sm += valid[n] ? __expf(vv[n] - mx) : 0.0f;
            #pragma unroll
            for (int msk = 1; msk < 16; msk <<= 1) sm += __shfl_xor(sm, msk);
            if (cgrp == 0) { redM[wn][rl] = mx; redS[wn][rl] = sm; }
        }
    }
    __syncthreads();
    if (tid < 128) {
        float m0 = redM[0][tid], s0 = redS[0][tid];
        float m1 = redM[1][tid], s1 = redS[1][tid];
        float M = fmaxf(m0, m1);
        float S = s0 * __expf(m0 - M) + s1 * __expf(m1 - M);
        size_t idx = (size_t)(rowbase + tid) * NB + nb;
        pmax[idx] = M;
        psum[idx] = S;
    }
}

// K5: per-row logsumexp over nbcnt partials -> loss_i.  grid 512 x 256
__global__ void k_rowlse(const float* __restrict__ pmax, const float* __restrict__ psum,
                         const float* __restrict__ ftl, float* __restrict__ lossi,
                         int nbcnt) {
    int row = blockIdx.x, tid = threadIdx.x;
    float M = -3.0e38f, S = 0.0f;
    for (int nb = tid; nb < nbcnt; nb += 256) {
        float m = pmax[(size_t)row * nbcnt + nb];
        float s = psum[(size_t)row * nbcnt + nb];
        float nm = fmaxf(M, m);
        S = S * __expf(M - nm) + s * __expf(m - nm);
        M = nm;
    }
    __shared__ float sM[256], sS[256];
    sM[tid] = M; sS[tid] = S;
    __syncthreads();
    for (int off = 128; off > 0; off >>= 1) {
        if (tid < off) {
            float m2 = sM[tid + off], s2 = sS[tid + off];
            float nm = fmaxf(sM[tid], m2);
            sS[tid] = sS[tid] * __expf(sM[tid] - nm) + s2 * __expf(m2 - nm);
            sM[tid] = nm;
        }
        __syncthreads();
    }
    if (tid == 0) lossi[row] = logf(sS[0]) + sM[0] - SCALE_F * ftl[row];
}

// K6: loss = mean(loss_i).  1 x 512
__global__ void k_final(const float* __restrict__ lossi, float* __restrict__ out) {
    __shared__ float s[512];
    int tid = threadIdx.x;
    s[tid] = lossi[tid];
    __syncthreads();
    for (int off = 256; off > 0; off >>= 1) {
        if (tid < off) s[tid] += s[tid + off];
        __syncthreads();
    }
    if (tid == 0) out[0] = s[0] / 512.0f;
}

extern "C" void kernel_launch(void* const* d_in, const int* in_sizes, int n_in,
                              void* d_out, int out_size, void* d_ws, size_t ws_size,
                              hipStream_t stream) {
    const float* x      = (const float*)d_in[0];
    const float* w      = (const float*)d_in[1];
    const float* t      = (const float*)d_in[2];
    const int*   target = (const int*)d_in[3];

    char* ws = (char*)d_ws;
    unsigned short* xn  = (unsigned short*)(ws + XN_OFF);
    float* xnorm = (float*)(ws + XNORM_OFF);
    float* wnorm = (float*)(ws + WNORM_OFF);
    float* tl    = (float*)(ws + TL_OFF);
    float* ctm   = (float*)(ws + CTM_OFF);
    float* ftl   = (float*)(ws + FTL_OFF);
    float* tnew  = (float*)(ws + TNEW_OFF);
    float* pmax  = (float*)(ws + PMAX_OFF);
    float* psum  = (float*)(ws + PSUM_OFF);
    float* lossi = (float*)(ws + LOSSI_OFF);
    unsigned short* wnb = (unsigned short*)(ws + WNBF_OFF);
    float* out   = (float*)d_out;

    bool fast = (ws_size >= WS_NEED_FAST);

    k_xnorm<<<dim3(N_ROWS), dim3(64), 0, stream>>>(x, xn, xnorm);
    if (fast) {
        k_wnorm_bf16<<<dim3(C_PAD / 4), dim3(256), 0, stream>>>(w, wnorm, wnb);
    } else {
        k_wnorm<<<dim3(C_CLS / 4), dim3(256), 0, stream>>>(w, wnorm);
    }
    k_tlogit<<<dim3(N_ROWS), dim3(64), 0, stream>>>(x, w, xnorm, wnorm, target, tl, ctm, ftl);
    k_tnew<<<dim3(1), dim3(512), 0, stream>>>(tl, t, tnew);
    if (fast) {
        k_gemm_stream<<<dim3(8 * NG), dim3(256), 0, stream>>>(xn, wnb, target, ctm, ftl, tnew, pmax, psum);
        k_rowlse<<<dim3(N_ROWS), dim3(256), 0, stream>>>(pmax, psum, ftl, lossi, NG);
    } else {
        k_gemm_epi<<<dim3(NB * 4), dim3(256), 0, stream>>>(xn, w, wnorm, target, ctm, ftl, tnew, pmax, psum);
        k_rowlse<<<dim3(N_ROWS), dim3(256), 0, stream>>>(pmax, psum, ftl, lossi, NB);
    }
    k_final<<<dim3(1), dim3(512), 0, stream>>>(lossi, out);
}

// Round 7
// 182.191 us; speedup vs baseline: 1.2901x; 1.0181x over previous
//
#include <hip/hip_runtime.h>
#include <hip/hip_bf16.h>
#include <stdint.h>

#define N_ROWS 512
#define D_DIM  512
#define C_CLS  100000
#define C_PAD  100096           // 391*256

#define SCALE_F    64.0f
#define EPS_F      1e-7f
#define COS_M_F    0.8775825618903728f
#define SIN_M_F    0.4794255386042030f
#define THRESH_F  -0.8775825618903728f
#define MM_F       0.2397127693021015f

#define NB 782          // fallback col-blocks of 128
#define NG 391          // fast-path col-groups of 256

// ---- ws layout (bytes) ----
#define XN_OFF     0                          // bf16 bits [512][512]
#define XNORM_OFF  (XN_OFF + 512*512*2)       // f32 [512]
#define WNORM_OFF  (XNORM_OFF + 2048)         // f32 [100096]
#define TL_OFF     (WNORM_OFF + 100096*4)     // f32 [512]
#define CTM_OFF    (TL_OFF + 2048)            // f32 [512]
#define FTL_OFF    (CTM_OFF + 2048)           // f32 [512]
#define TNEW_OFF   (FTL_OFF + 2048)           // f32 [1] (padded)
#define PMAX_OFF   (TNEW_OFF + 256)           // f32 [512][NB] (>= [512][NG])
#define PSUM_OFF   (PMAX_OFF + 512*NB*4)      // f32 [512][NB]
#define LOSSI_OFF  (PSUM_OFF + 512*NB*4)      // f32 [512]
#define WNBF_OFF   (LOSSI_OFF + 2048)         // bf16 bits [100096][512] (fast path)
#define WS_NEED_FAST ((size_t)WNBF_OFF + (size_t)C_PAD*512*2)

typedef __attribute__((ext_vector_type(8))) short bf16x8;
typedef __attribute__((ext_vector_type(4))) float f32x4;

#define GLOAD_LDS16(gp, lp) \
    __builtin_amdgcn_global_load_lds((const __attribute__((address_space(1))) void*)(gp), \
                                     (__attribute__((address_space(3))) void*)(lp), 16, 0, 0)

__device__ inline unsigned short f2bf(float f) {
    union { float f; unsigned int u; } a; a.f = f;
    unsigned int r = (a.u + 0x7FFFu + ((a.u >> 16) & 1u)) >> 16;
    return (unsigned short)r;
}

__device__ inline float wave_sum64(float v) {
    #pragma unroll
    for (int m = 1; m < 64; m <<= 1) v += __shfl_xor(v, m);
    return v;
}

// K1: x row norms + xn bf16.  grid 512 x 64
__global__ void k_xnorm(const float* __restrict__ x,
                        unsigned short* __restrict__ xn,
                        float* __restrict__ xnorm) {
    int row = blockIdx.x;
    int lane = threadIdx.x;
    const float* xr = x + row * D_DIM + lane * 8;
    float4 v0 = *(const float4*)(xr);
    float4 v1 = *(const float4*)(xr + 4);
    float s = v0.x*v0.x + v0.y*v0.y + v0.z*v0.z + v0.w*v0.w
            + v1.x*v1.x + v1.y*v1.y + v1.z*v1.z + v1.w*v1.w;
    s = wave_sum64(s);
    float nrm = sqrtf(s);
    if (lane == 0) xnorm[row] = nrm;
    float inv = 1.0f / nrm;
    union { unsigned short h[8]; uint4 q; } u;
    u.h[0]=f2bf(v0.x*inv); u.h[1]=f2bf(v0.y*inv); u.h[2]=f2bf(v0.z*inv); u.h[3]=f2bf(v0.w*inv);
    u.h[4]=f2bf(v1.x*inv); u.h[5]=f2bf(v1.y*inv); u.h[6]=f2bf(v1.z*inv); u.h[7]=f2bf(v1.w*inv);
    *(uint4*)(xn + row * D_DIM + lane * 8) = u.q;
}

// K2 (fast): weight row norms + normalized bf16 W (pad rows zeroed).
// grid 25024 x 256 (wave per row)
__global__ void k_wnorm_bf16(const float* __restrict__ w, float* __restrict__ wnorm,
                             unsigned short* __restrict__ wnb) {
    int row = blockIdx.x * 4 + (threadIdx.x >> 6);
    int lane = threadIdx.x & 63;
    if (row < C_CLS) {
        const float* wr = w + (size_t)row * D_DIM + lane * 8;
        float4 v0 = *(const float4*)(wr);
        float4 v1 = *(const float4*)(wr + 4);
        float s = v0.x*v0.x + v0.y*v0.y + v0.z*v0.z + v0.w*v0.w
                + v1.x*v1.x + v1.y*v1.y + v1.z*v1.z + v1.w*v1.w;
        s = wave_sum64(s);
        float nrm = sqrtf(s);
        if (lane == 0) wnorm[row] = nrm;
        float inv = 1.0f / nrm;
        union { unsigned short h[8]; uint4 q; } u;
        u.h[0]=f2bf(v0.x*inv); u.h[1]=f2bf(v0.y*inv); u.h[2]=f2bf(v0.z*inv); u.h[3]=f2bf(v0.w*inv);
        u.h[4]=f2bf(v1.x*inv); u.h[5]=f2bf(v1.y*inv); u.h[6]=f2bf(v1.z*inv); u.h[7]=f2bf(v1.w*inv);
        *(uint4*)(wnb + (size_t)row * D_DIM + lane * 8) = u.q;
    } else {
        uint4 z = {0u, 0u, 0u, 0u};
        *(uint4*)(wnb + (size_t)row * D_DIM + lane * 8) = z;
    }
}

// K2 (fallback): weight row norms only.  grid 25000 x 256
__global__ void k_wnorm(const float* __restrict__ w, float* __restrict__ wnorm) {
    int row = blockIdx.x * 4 + (threadIdx.x >> 6);
    int lane = threadIdx.x & 63;
    const float* wr = w + (size_t)row * D_DIM + lane * 8;
    float4 v0 = *(const float4*)(wr);
    float4 v1 = *(const float4*)(wr + 4);
    float s = v0.x*v0.x + v0.y*v0.y + v0.z*v0.z + v0.w*v0.w
            + v1.x*v1.x + v1.y*v1.y + v1.z*v1.z + v1.w*v1.w;
    s = wave_sum64(s);
    if (lane == 0) wnorm[row] = sqrtf(s);
}

// K3: per-row target logit + margin terms (exact f32).  grid 512 x 64
__global__ void k_tlogit(const float* __restrict__ x, const float* __restrict__ w,
                         const float* __restrict__ xnorm, const float* __restrict__ wnorm,
                         const int* __restrict__ target,
                         float* __restrict__ tl, float* __restrict__ ctm,
                         float* __restrict__ ftl) {
    int row = blockIdx.x;
    int lane = threadIdx.x;
    int tgt = target[row];
    const float* xr = x + row * D_DIM + lane * 8;
    const float* wr = w + (size_t)tgt * D_DIM + lane * 8;
    float4 a0 = *(const float4*)(xr),     a1 = *(const float4*)(xr + 4);
    float4 b0 = *(const float4*)(wr),     b1 = *(const float4*)(wr + 4);
    float s = a0.x*b0.x + a0.y*b0.y + a0.z*b0.z + a0.w*b0.w
            + a1.x*b1.x + a1.y*b1.y + a1.z*b1.z + a1.w*b1.w;
    s = wave_sum64(s);
    if (lane == 0) {
        float c = s / (xnorm[row] * wnorm[tgt]);
        c = fminf(fmaxf(c, -1.0f + EPS_F), 1.0f - EPS_F);
        float sn = sqrtf(fmaxf(1.0f - c * c, 0.0f));
        float cm = c * COS_M_F - sn * SIN_M_F;
        tl[row]  = c;
        ctm[row] = cm;
        ftl[row] = (c > THRESH_F) ? cm : (c - MM_F);
    }
}

// K3b: t_new = mean(tl)*0.01 + 0.99*t.  1 x 512
__global__ void k_tnew(const float* __restrict__ tl, const float* __restrict__ t,
                       float* __restrict__ tnew) {
    __shared__ float s[512];
    int tid = threadIdx.x;
    s[tid] = tl[tid];
    __syncthreads();
    for (int off = 256; off > 0; off >>= 1) {
        if (tid < off) s[tid] += s[tid + off];
        __syncthreads();
    }
    if (tid == 0) tnew[0] = (s[0] / 512.0f) * 0.01f + 0.99f * t[0];
}

// ---------------------------------------------------------------------------
// K4 fast: barrier-free streaming GEMM, occupancy-tuned.
//  - block = 4 waves, 64 A-rows, 256 classes; A staged in TWO 32KB K-halves
//    (frag-major [kk][m][1KB], conflict-free ds_read_b128), half-1 staging
//    issued BEFORE half-0 compute; 3 barriers total; ~35KB LDS -> 4 blocks/CU.
//  - B frags stream global->VGPR, depth-3 register buffer; af 1-ahead.
//  - setprio(1) around MFMA clusters (desynchronized waves, attn-like regime).
// grid 3128 x 256
// ---------------------------------------------------------------------------
__global__ __launch_bounds__(256, 4) void k_gemm_stream(
        const unsigned short* __restrict__ xn,    // bf16 [512][512]
        const unsigned short* __restrict__ wnb,   // bf16 [100096][512], normalized
        const int* __restrict__ target,
        const float* __restrict__ ctm,
        const float* __restrict__ ftl,
        const float* __restrict__ tnew,
        float* __restrict__ pmax, float* __restrict__ psum) {
    __shared__ unsigned short As[2][8 * 4 * 512];   // 2 x 16 KB halves
    __shared__ int   tgt_s[64];
    __shared__ float ctm_s[64];
    __shared__ float ftl_s[64];
    __shared__ float redM[4][64];
    __shared__ float redS[4][64];

    // XCD remap: 3128 = 8*391; all 8 mb-siblings of an ng share one XCD.
    int bx = blockIdx.x;
    int logical = (bx & 7) * 391 + (bx >> 3);
    int ng = logical >> 3, mb = logical & 7;
    int rowbase = mb * 64;

    int tid = threadIdx.x;
    int lane = tid & 63, wid = tid >> 6;
    int fr = lane & 15, rgrp = lane >> 4;
    int cb = ng * 256 + wid * 64;              // this wave's first class

    if (tid < 64) {
        int rg = rowbase + tid;
        tgt_s[tid] = target[rg];
        ctm_s[tid] = ctm[rg];
        ftl_s[tid] = ftl[rg];
    }

    const char* Ab = (const char*)xn;     // row stride 1024 B
    const char* Bb = (const char*)wnb;    // row stride 1024 B

    // ---- B lane base pointers (per n-tile j): row = cb + j*16 + fr ----
    const char* bptr[4];
    #pragma unroll
    for (int j = 0; j < 4; j++)
        bptr[j] = Bb + (size_t)(cb + j * 16 + fr) * 1024 + rgrp * 16;

    // ---- B preloads kk=0,1,2 (depth-3) ----
    bf16x8 bv[3][4];
    #pragma unroll
    for (int d = 0; d < 3; d++)
        #pragma unroll
        for (int j = 0; j < 4; j++)
            bv[d][j] = *(const bf16x8*)(bptr[j] + d * 64);

    // ---- stage A half h: 32 chunks of 1 KB, chunk c = kk*4+m ----
    // staging lane writes 16B: frag-row lane>>2, k-slot lane&3.
    int asrow = lane >> 2, askb = (lane & 3) * 16;
    #pragma unroll
    for (int cc = 0; cc < 8; ++cc) {                   // half 0
        int c = wid * 8 + cc;
        int kk = c >> 2, m = c & 3;
        GLOAD_LDS16(Ab + (size_t)(rowbase + m * 16 + asrow) * 1024 + kk * 64 + askb,
                    (char*)As[0] + c * 1024);
    }
    __syncthreads();                                    // half-0 staged

    // issue half-1 staging now; it lands under half-0's compute
    #pragma unroll
    for (int cc = 0; cc < 8; ++cc) {
        int c = wid * 8 + cc;
        int kk = c >> 2, m = c & 3;
        GLOAD_LDS16(Ab + (size_t)(rowbase + m * 16 + asrow) * 1024 + (8 + kk) * 64 + askb,
                    (char*)As[1] + c * 1024);
    }

    float tn = tnew[0];
    int albase = fr * 64 + rgrp * 16;          // reader offset within a frag

    f32x4 acc[4][4];                           // [m][j]
    #pragma unroll
    for (int m = 0; m < 4; m++)
        #pragma unroll
        for (int j = 0; j < 4; j++)
            acc[m][j] = (f32x4){0.f, 0.f, 0.f, 0.f};

    bf16x8 af[2][4];
    #pragma unroll
    for (int m = 0; m < 4; m++)
        af[0][m] = *(const bf16x8*)((const char*)As[0] + m * 1024 + albase);

    // ---- half 0: kk = 0..7 ----
    #pragma unroll
    for (int kk = 0; kk < 8; ++kk) {
        int cur = kk & 1;
        if (kk < 7) {
            #pragma unroll
            for (int m = 0; m < 4; m++)
                af[cur ^ 1][m] = *(const bf16x8*)((const char*)As[0]
                                 + ((kk + 1) * 4 + m) * 1024 + albase);
        }
        __builtin_amdgcn_s_setprio(1);
        #pragma unroll
        for (int m = 0; m < 4; m++)
            #pragma unroll
            for (int j = 0; j < 4; j++)
                acc[m][j] = __builtin_amdgcn_mfma_f32_16x16x32_bf16(
                                af[cur][m], bv[kk % 3][j], acc[m][j], 0, 0, 0);
        __builtin_amdgcn_s_setprio(0);
        {   // prefetch B for kk+3
            #pragma unroll
            for (int j = 0; j < 4; j++)
                bv[kk % 3][j] = *(const bf16x8*)(bptr[j] + (kk + 3) * 64);
        }
    }
    __syncthreads();                                    // half-1 staged

    #pragma unroll
    for (int m = 0; m < 4; m++)
        af[0][m] = *(const bf16x8*)((const char*)As[1] + m * 1024 + albase);

    // ---- half 1: kk = 8..15 ----
    #pragma unroll
    for (int kk = 8; kk < 16; ++kk) {
        int lk = kk - 8;
        int cur = lk & 1;
        if (lk < 7) {
            #pragma unroll
            for (int m = 0; m < 4; m++)
                af[cur ^ 1][m] = *(const bf16x8*)((const char*)As[1]
                                 + ((lk + 1) * 4 + m) * 1024 + albase);
        }
        __builtin_amdgcn_s_setprio(1);
        #pragma unroll
        for (int m = 0; m < 4; m++)
            #pragma unroll
            for (int j = 0; j < 4; j++)
                acc[m][j] = __builtin_amdgcn_mfma_f32_16x16x32_bf16(
                                af[cur][m], bv[kk % 3][j], acc[m][j], 0, 0, 0);
        __builtin_amdgcn_s_setprio(0);
        if (kk < 13) {
            #pragma unroll
            for (int j = 0; j < 4; j++)
                bv[kk % 3][j] = *(const bf16x8*)(bptr[j] + (kk + 3) * 64);
        }
    }

    // ---- epilogue: transform in place, then row (max, sumexp) ----
    // C/D layout: col = cb + j*16 + fr, row = m*16 + rgrp*4 + reg.
    #pragma unroll
    for (int m = 0; m < 4; m++) {
        #pragma unroll
        for (int reg = 0; reg < 4; reg++) {
            int rl = m * 16 + rgrp * 4 + reg;
            int tr = tgt_s[rl];
            float cm = ctm_s[rl];
            float ft = ftl_s[rl];
            #pragma unroll
            for (int j = 0; j < 4; j++) {
                int col = cb + j * 16 + fr;
                float c = acc[m][j][reg];
                c = fminf(fmaxf(c, -1.0f + EPS_F), 1.0f - EPS_F);
                float v = (c > cm) ? c * (tn + c) : c;
                v *= SCALE_F;
                v = (col == tr) ? ft * SCALE_F : v;
                v = (col < C_CLS) ? v : -3.0e38f;
                acc[m][j][reg] = v;
            }
        }
    }
    #pragma unroll
    for (int m = 0; m < 4; m++) {
        #pragma unroll
        for (int reg = 0; reg < 4; reg++) {
            float mx = fmaxf(fmaxf(acc[m][0][reg], acc[m][1][reg]),
                             fmaxf(acc[m][2][reg], acc[m][3][reg]));
            #pragma unroll
            for (int msk = 1; msk < 16; msk <<= 1) mx = fmaxf(mx, __shfl_xor(mx, msk));
            float sm = __expf(acc[m][0][reg] - mx) + __expf(acc[m][1][reg] - mx)
                     + __expf(acc[m][2][reg] - mx) + __expf(acc[m][3][reg] - mx);
            #pragma unroll
            for (int msk = 1; msk < 16; msk <<= 1) sm += __shfl_xor(sm, msk);
            if (fr == 0) {
                int rl = m * 16 + rgrp * 4 + reg;
                redM[wid][rl] = mx;
                redS[wid][rl] = sm;
            }
        }
    }
    __syncthreads();
    if (tid < 64) {
        float M = fmaxf(fmaxf(redM[0][tid], redM[1][tid]),
                        fmaxf(redM[2][tid], redM[3][tid]));
        float S = redS[0][tid] * __expf(redM[0][tid] - M)
                + redS[1][tid] * __expf(redM[1][tid] - M)
                + redS[2][tid] * __expf(redM[2][tid] - M)
                + redS[3][tid] * __expf(redM[3][tid] - M);
        size_t odx = (size_t)(rowbase + tid) * NG + ng;
        pmax[odx] = M;
        psum[odx] = S;
    }
}

// ---------------------------------------------------------------------------
// K4 fallback (round-2 version): f32 W load + on-the-fly normalize/convert.
// grid NB*4 x 256, partials [512][NB]
// ---------------------------------------------------------------------------
__global__ __launch_bounds__(256) void k_gemm_epi(
        const unsigned short* __restrict__ xn,
        const float* __restrict__ w,
        const float* __restrict__ wnorm,
        const int* __restrict__ target,
        const float* __restrict__ ctm,
        const float* __restrict__ ftl,
        const float* __restrict__ tnew,
        float* __restrict__ pmax, float* __restrict__ psum) {
    __shared__ unsigned short As[128 * 32];
    __shared__ unsigned short Bs[128 * 32];
    __shared__ int   tgt_s[128];
    __shared__ float ctm_s[128];
    __shared__ float ftl_s[128];
    __shared__ float redM[2][128];
    __shared__ float redS[2][128];

    int bx = blockIdx.x;
    int nb = bx >> 2, mb = bx & 3;
    int rowbase = mb * 128, colbase = nb * 128;
    int tid = threadIdx.x;
    int lane = tid & 63, wid = tid >> 6;
    int wm = wid >> 1, wn = wid & 1;

    if (tid < 128) {
        int rg = rowbase + tid;
        tgt_s[tid] = target[rg];
        ctm_s[tid] = ctm[rg];
        ftl_s[tid] = ftl[rg];
    }
    float tn = tnew[0];

    int srow = tid >> 1;
    int skq  = (tid & 1) * 16;
    int cg = colbase + srow;
    float wscale = 0.0f;
    if (cg < C_CLS) wscale = 1.0f / wnorm[cg];

    f32x4 acc[4][4];
    #pragma unroll
    for (int m = 0; m < 4; m++)
        #pragma unroll
        for (int n = 0; n < 4; n++)
            acc[m][n] = (f32x4){0.f, 0.f, 0.f, 0.f};

    for (int kt = 0; kt < D_DIM / 32; ++kt) {
        int k0 = kt * 32;
        __syncthreads();
        {
            const uint4* src = (const uint4*)(xn + (rowbase + srow) * D_DIM + k0 + skq);
            uint4 a0 = src[0], a1 = src[1];
            *(uint4*)(&As[srow * 32 + skq])     = a0;
            *(uint4*)(&As[srow * 32 + skq + 8]) = a1;
        }
        {
            union { unsigned short h[16]; uint4 q[2]; } pk;
            if (cg < C_CLS) {
                const float4* src = (const float4*)(w + (size_t)cg * D_DIM + k0 + skq);
                #pragma unroll
                for (int q = 0; q < 4; q++) {
                    float4 v = src[q];
                    pk.h[q*4+0] = f2bf(v.x * wscale);
                    pk.h[q*4+1] = f2bf(v.y * wscale);
                    pk.h[q*4+2] = f2bf(v.z * wscale);
                    pk.h[q*4+3] = f2bf(v.w * wscale);
                }
            } else {
                #pragma unroll
                for (int j = 0; j < 16; j++) pk.h[j] = 0;
            }
            *(uint4*)(&Bs[srow * 32 + skq])     = pk.q[0];
            *(uint4*)(&Bs[srow * 32 + skq + 8]) = pk.q[1];
        }
        __syncthreads();
        int fr = lane & 15, kg = (lane >> 4) * 8;
        bf16x8 af[4], bfr[4];
        #pragma unroll
        for (int m = 0; m < 4; m++)
            af[m] = *(const bf16x8*)(&As[(wm * 64 + m * 16 + fr) * 32 + kg]);
        #pragma unroll
        for (int n = 0; n < 4; n++)
            bfr[n] = *(const bf16x8*)(&Bs[(wn * 64 + n * 16 + fr) * 32 + kg]);
        #pragma unroll
        for (int m = 0; m < 4; m++)
            #pragma unroll
            for (int n = 0; n < 4; n++)
                acc[m][n] = __builtin_amdgcn_mfma_f32_16x16x32_bf16(af[m], bfr[n], acc[m][n], 0, 0, 0);
    }

    int cgrp = lane & 15, rgrp = lane >> 4;
    #pragma unroll
    for (int m = 0; m < 4; m++) {
        #pragma unroll
        for (int reg = 0; reg < 4; reg++) {
            int rl = wm * 64 + m * 16 + rgrp * 4 + reg;
            int tr = tgt_s[rl];
            float cm = ctm_s[rl];
            float vv[4];
            bool valid[4];
            #pragma unroll
            for (int n = 0; n < 4; n++) {
                int cl = wn * 64 + n * 16 + cgrp;
                int cgl = colbase + cl;
                float c = acc[m][n][reg];
                c = fminf(fmaxf(c, -1.0f + EPS_F), 1.0f - EPS_F);
                float v;
                if (cgl >= C_CLS)      { v = -3.0e38f; valid[n] = false; }
                else if (cgl == tr)    { v = ftl_s[rl] * SCALE_F; valid[n] = true; }
                else {
                    v = (c > cm) ? c * (tn + c) : c;
                    v *= SCALE_F;
                    valid[n] = true;
                }
                vv[n] = v;
            }
            float mx = fmaxf(fmaxf(vv[0], vv[1]), fmaxf(vv[2], vv[3]));
            #pragma unroll
            for (int msk = 1; msk < 16; msk <<= 1) mx = fmaxf(mx, __shfl_xor(mx, msk));
            float sm = 0.0f;
            #pragma unroll
            for (int n = 0; n < 4; n++) sm += valid[n] ? __expf(vv[n] - mx) : 0.0f;
            #pragma unroll
            for (int msk = 1; msk < 16; msk <<= 1) sm += __shfl_xor(sm, msk);
            if (cgrp == 0) { redM[wn][rl] = mx; redS[wn][rl] = sm; }
        }
    }
    __syncthreads();
    if (tid < 128) {
        float m0 = redM[0][tid], s0 = redS[0][tid];
        float m1 = redM[1][tid], s1 = redS[1][tid];
        float M = fmaxf(m0, m1);
        float S = s0 * __expf(m0 - M) + s1 * __expf(m1 - M);
        size_t idx = (size_t)(rowbase + tid) * NB + nb;
        pmax[idx] = M;
        psum[idx] = S;
    }
}

// K5: per-row logsumexp over nbcnt partials -> loss_i.  grid 512 x 256
__global__ void k_rowlse(const float* __restrict__ pmax, const float* __restrict__ psum,
                         const float* __restrict__ ftl, float* __restrict__ lossi,
                         int nbcnt) {
    int row = blockIdx.x, tid = threadIdx.x;
    float M = -3.0e38f, S = 0.0f;
    for (int nb = tid; nb < nbcnt; nb += 256) {
        float m = pmax[(size_t)row * nbcnt + nb];
        float s = psum[(size_t)row * nbcnt + nb];
        float nm = fmaxf(M, m);
        S = S * __expf(M - nm) + s * __expf(m - nm);
        M = nm;
    }
    __shared__ float sM[256], sS[256];
    sM[tid] = M; sS[tid] = S;
    __syncthreads();
    for (int off = 128; off > 0; off >>= 1) {
        if (tid < off) {
            float m2 = sM[tid + off], s2 = sS[tid + off];
            float nm = fmaxf(sM[tid], m2);
            sS[tid] = sS[tid] * __expf(sM[tid] - nm) + s2 * __expf(m2 - nm);
            sM[tid] = nm;
        }
        __syncthreads();
    }
    if (tid == 0) lossi[row] = logf(sS[0]) + sM[0] - SCALE_F * ftl[row];
}

// K6: loss = mean(loss_i).  1 x 512
__global__ void k_final(const float* __restrict__ lossi, float* __restrict__ out) {
    __shared__ float s[512];
    int tid = threadIdx.x;
    s[tid] = lossi[tid];
    __syncthreads();
    for (int off = 256; off > 0; off >>= 1) {
        if (tid < off) s[tid] += s[tid + off];
        __syncthreads();
    }
    if (tid == 0) out[0] = s[0] / 512.0f;
}

extern "C" void kernel_launch(void* const* d_in, const int* in_sizes, int n_in,
                              void* d_out, int out_size, void* d_ws, size_t ws_size,
                              hipStream_t stream) {
    const float* x      = (const float*)d_in[0];
    const float* w      = (const float*)d_in[1];
    const float* t      = (const float*)d_in[2];
    const int*   target = (const int*)d_in[3];

    char* ws = (char*)d_ws;
    unsigned short* xn  = (unsigned short*)(ws + XN_OFF);
    float* xnorm = (float*)(ws + XNORM_OFF);
    float* wnorm = (float*)(ws + WNORM_OFF);
    float* tl    = (float*)(ws + TL_OFF);
    float* ctm   = (float*)(ws + CTM_OFF);
    float* ftl   = (float*)(ws + FTL_OFF);
    float* tnew  = (float*)(ws + TNEW_OFF);
    float* pmax  = (float*)(ws + PMAX_OFF);
    float* psum  = (float*)(ws + PSUM_OFF);
    float* lossi = (float*)(ws + LOSSI_OFF);
    unsigned short* wnb = (unsigned short*)(ws + WNBF_OFF);
    float* out   = (float*)d_out;

    bool fast = (ws_size >= WS_NEED_FAST);

    k_xnorm<<<dim3(N_ROWS), dim3(64), 0, stream>>>(x, xn, xnorm);
    if (fast) {
        k_wnorm_bf16<<<dim3(C_PAD / 4), dim3(256), 0, stream>>>(w, wnorm, wnb);
    } else {
        k_wnorm<<<dim3(C_CLS / 4), dim3(256), 0, stream>>>(w, wnorm);
    }
    k_tlogit<<<dim3(N_ROWS), dim3(64), 0, stream>>>(x, w, xnorm, wnorm, target, tl, ctm, ftl);
    k_tnew<<<dim3(1), dim3(512), 0, stream>>>(tl, t, tnew);
    if (fast) {
        k_gemm_stream<<<dim3(8 * NG), dim3(256), 0, stream>>>(xn, wnb, target, ctm, ftl, tnew, pmax, psum);
        k_rowlse<<<dim3(N_ROWS), dim3(256), 0, stream>>>(pmax, psum, ftl, lossi, NG);
    } else {
        k_gemm_epi<<<dim3(NB * 4), dim3(256), 0, stream>>>(xn, w, wnorm, target, ctm, ftl, tnew, pmax, psum);
        k_rowlse<<<dim3(N_ROWS), dim3(256), 0, stream>>>(pmax, psum, ftl, lossi, NB);
    }
    k_final<<<dim3(1), dim3(512), 0, stream>>>(lossi, out);
}

// Round 8
// 180.401 us; speedup vs baseline: 1.3029x; 1.0099x over previous
//
#include <hip/hip_runtime.h>
#include <hip/hip_bf16.h>
#include <stdint.h>

#define N_ROWS 512
#define D_DIM  512
#define C_CLS  100000
#define C_PAD  100096           // 391*256

#define SCALE_F    64.0f
#define EPS_F      1e-7f
#define COS_M_F    0.8775825618903728f
#define SIN_M_F    0.4794255386042030f
#define THRESH_F  -0.8775825618903728f
#define MM_F       0.2397127693021015f

#define NB 782          // fallback col-blocks of 128
#define NG 391          // fast-path col-groups of 256

// ---- ws layout (bytes) ----
#define XN_OFF     0                          // bf16 bits [512][512]
#define XNORM_OFF  (XN_OFF + 512*512*2)       // f32 [512]
#define WNORM_OFF  (XNORM_OFF + 2048)         // f32 [100096]
#define TL_OFF     (WNORM_OFF + 100096*4)     // f32 [512]
#define CTM_OFF    (TL_OFF + 2048)            // f32 [512]
#define FTL_OFF    (CTM_OFF + 2048)           // f32 [512]
#define TNEW_OFF   (FTL_OFF + 2048)           // f32 [1] (padded)
#define PMAX_OFF   (TNEW_OFF + 256)           // f32 [512][NB] (>= [512][NG])
#define PSUM_OFF   (PMAX_OFF + 512*NB*4)      // f32 [512][NB]
#define LOSSI_OFF  (PSUM_OFF + 512*NB*4)      // f32 [512]
#define WNBF_OFF   (LOSSI_OFF + 2048)         // bf16 bits [100096][512] (fast path)
#define WS_NEED_FAST ((size_t)WNBF_OFF + (size_t)C_PAD*512*2)

typedef __attribute__((ext_vector_type(8))) short bf16x8;
typedef __attribute__((ext_vector_type(4))) float f32x4;

#define GLOAD_LDS16(gp, lp) \
    __builtin_amdgcn_global_load_lds((const __attribute__((address_space(1))) void*)(gp), \
                                     (__attribute__((address_space(3))) void*)(lp), 16, 0, 0)

__device__ inline unsigned short f2bf(float f) {
    union { float f; unsigned int u; } a; a.f = f;
    unsigned int r = (a.u + 0x7FFFu + ((a.u >> 16) & 1u)) >> 16;
    return (unsigned short)r;
}

__device__ inline float wave_sum64(float v) {
    #pragma unroll
    for (int m = 1; m < 64; m <<= 1) v += __shfl_xor(v, m);
    return v;
}

// K1: x row norms + xn bf16.  grid 512 x 64
__global__ void k_xnorm(const float* __restrict__ x,
                        unsigned short* __restrict__ xn,
                        float* __restrict__ xnorm) {
    int row = blockIdx.x;
    int lane = threadIdx.x;
    const float* xr = x + row * D_DIM + lane * 8;
    float4 v0 = *(const float4*)(xr);
    float4 v1 = *(const float4*)(xr + 4);
    float s = v0.x*v0.x + v0.y*v0.y + v0.z*v0.z + v0.w*v0.w
            + v1.x*v1.x + v1.y*v1.y + v1.z*v1.z + v1.w*v1.w;
    s = wave_sum64(s);
    float nrm = sqrtf(s);
    if (lane == 0) xnorm[row] = nrm;
    float inv = 1.0f / nrm;
    union { unsigned short h[8]; uint4 q; } u;
    u.h[0]=f2bf(v0.x*inv); u.h[1]=f2bf(v0.y*inv); u.h[2]=f2bf(v0.z*inv); u.h[3]=f2bf(v0.w*inv);
    u.h[4]=f2bf(v1.x*inv); u.h[5]=f2bf(v1.y*inv); u.h[6]=f2bf(v1.z*inv); u.h[7]=f2bf(v1.w*inv);
    *(uint4*)(xn + row * D_DIM + lane * 8) = u.q;
}

// K2 (fast): weight row norms + normalized bf16 W (pad rows zeroed).
// grid 25024 x 256 (wave per row)
__global__ void k_wnorm_bf16(const float* __restrict__ w, float* __restrict__ wnorm,
                             unsigned short* __restrict__ wnb) {
    int row = blockIdx.x * 4 + (threadIdx.x >> 6);
    int lane = threadIdx.x & 63;
    if (row < C_CLS) {
        const float* wr = w + (size_t)row * D_DIM + lane * 8;
        float4 v0 = *(const float4*)(wr);
        float4 v1 = *(const float4*)(wr + 4);
        float s = v0.x*v0.x + v0.y*v0.y + v0.z*v0.z + v0.w*v0.w
                + v1.x*v1.x + v1.y*v1.y + v1.z*v1.z + v1.w*v1.w;
        s = wave_sum64(s);
        float nrm = sqrtf(s);
        if (lane == 0) wnorm[row] = nrm;
        float inv = 1.0f / nrm;
        union { unsigned short h[8]; uint4 q; } u;
        u.h[0]=f2bf(v0.x*inv); u.h[1]=f2bf(v0.y*inv); u.h[2]=f2bf(v0.z*inv); u.h[3]=f2bf(v0.w*inv);
        u.h[4]=f2bf(v1.x*inv); u.h[5]=f2bf(v1.y*inv); u.h[6]=f2bf(v1.z*inv); u.h[7]=f2bf(v1.w*inv);
        *(uint4*)(wnb + (size_t)row * D_DIM + lane * 8) = u.q;
    } else {
        uint4 z = {0u, 0u, 0u, 0u};
        *(uint4*)(wnb + (size_t)row * D_DIM + lane * 8) = z;
    }
}

// K2 (fallback): weight row norms only.  grid 25000 x 256
__global__ void k_wnorm(const float* __restrict__ w, float* __restrict__ wnorm) {
    int row = blockIdx.x * 4 + (threadIdx.x >> 6);
    int lane = threadIdx.x & 63;
    const float* wr = w + (size_t)row * D_DIM + lane * 8;
    float4 v0 = *(const float4*)(wr);
    float4 v1 = *(const float4*)(wr + 4);
    float s = v0.x*v0.x + v0.y*v0.y + v0.z*v0.z + v0.w*v0.w
            + v1.x*v1.x + v1.y*v1.y + v1.z*v1.z + v1.w*v1.w;
    s = wave_sum64(s);
    if (lane == 0) wnorm[row] = sqrtf(s);
}

// K3: per-row target logit + margin terms (exact f32).  grid 512 x 64
__global__ void k_tlogit(const float* __restrict__ x, const float* __restrict__ w,
                         const float* __restrict__ xnorm, const float* __restrict__ wnorm,
                         const int* __restrict__ target,
                         float* __restrict__ tl, float* __restrict__ ctm,
                         float* __restrict__ ftl) {
    int row = blockIdx.x;
    int lane = threadIdx.x;
    int tgt = target[row];
    const float* xr = x + row * D_DIM + lane * 8;
    const float* wr = w + (size_t)tgt * D_DIM + lane * 8;
    float4 a0 = *(const float4*)(xr),     a1 = *(const float4*)(xr + 4);
    float4 b0 = *(const float4*)(wr),     b1 = *(const float4*)(wr + 4);
    float s = a0.x*b0.x + a0.y*b0.y + a0.z*b0.z + a0.w*b0.w
            + a1.x*b1.x + a1.y*b1.y + a1.z*b1.z + a1.w*b1.w;
    s = wave_sum64(s);
    if (lane == 0) {
        float c = s / (xnorm[row] * wnorm[tgt]);
        c = fminf(fmaxf(c, -1.0f + EPS_F), 1.0f - EPS_F);
        float sn = sqrtf(fmaxf(1.0f - c * c, 0.0f));
        float cm = c * COS_M_F - sn * SIN_M_F;
        tl[row]  = c;
        ctm[row] = cm;
        ftl[row] = (c > THRESH_F) ? cm : (c - MM_F);
    }
}

// K3b: t_new = mean(tl)*0.01 + 0.99*t.  1 x 512
__global__ void k_tnew(const float* __restrict__ tl, const float* __restrict__ t,
                       float* __restrict__ tnew) {
    __shared__ float s[512];
    int tid = threadIdx.x;
    s[tid] = tl[tid];
    __syncthreads();
    for (int off = 256; off > 0; off >>= 1) {
        if (tid < off) s[tid] += s[tid + off];
        __syncthreads();
    }
    if (tid == 0) tnew[0] = (s[0] / 512.0f) * 0.01f + 0.99f * t[0];
}

// ---------------------------------------------------------------------------
// K4 fast: barrier-free streaming GEMM, 8-WAVE blocks for occupancy.
//  - block = 8 waves (512 thr), 64 A-rows, 256 classes; wave owns 32 classes.
//  - A staged in two 32KB K-halves (frag-major [kk][m][1KB], conflict-free
//    ds_read_b128); half-1 staging issued before half-0 compute.
//  - 64KB A + ~5KB extras -> 2 blocks/CU = 16 waves/CU = 4 waves/SIMD
//    (vs 2 waves/SIMD with 4-wave blocks) -- the occupancy lever.
//  - B frags stream global->VGPR, depth-3 ring; af 1-ahead ds_read.
// grid 3128 x 512
// ---------------------------------------------------------------------------
__global__ __launch_bounds__(512, 4) void k_gemm_stream(
        const unsigned short* __restrict__ xn,    // bf16 [512][512]
        const unsigned short* __restrict__ wnb,   // bf16 [100096][512], normalized
        const int* __restrict__ target,
        const float* __restrict__ ctm,
        const float* __restrict__ ftl,
        const float* __restrict__ tnew,
        float* __restrict__ pmax, float* __restrict__ psum) {
    __shared__ unsigned short As[2][8 * 4 * 512];   // 2 x 32 KB K-halves
    __shared__ int   tgt_s[64];
    __shared__ float ctm_s[64];
    __shared__ float ftl_s[64];
    __shared__ float redM[8][64];
    __shared__ float redS[8][64];

    // XCD remap: 3128 = 8*391; all 8 mb-siblings of an ng share one XCD.
    int bx = blockIdx.x;
    int logical = (bx & 7) * 391 + (bx >> 3);
    int ng = logical >> 3, mb = logical & 7;
    int rowbase = mb * 64;

    int tid = threadIdx.x;
    int lane = tid & 63, wid = tid >> 6;       // wid 0..7
    int fr = lane & 15, rgrp = lane >> 4;
    int cb = ng * 256 + wid * 32;              // this wave's first class (32 classes)

    if (tid < 64) {
        int rg = rowbase + tid;
        tgt_s[tid] = target[rg];
        ctm_s[tid] = ctm[rg];
        ftl_s[tid] = ftl[rg];
    }

    const char* Ab = (const char*)xn;     // row stride 1024 B
    const char* Bb = (const char*)wnb;    // row stride 1024 B

    // ---- B lane base pointers (j-tile j): row = cb + j*16 + fr ----
    const char* bptr[2];
    #pragma unroll
    for (int j = 0; j < 2; j++)
        bptr[j] = Bb + (size_t)(cb + j * 16 + fr) * 1024 + rgrp * 16;

    // ---- B preloads kk=0,1,2 (depth-3 ring) ----
    bf16x8 bv[3][2];
    #pragma unroll
    for (int d = 0; d < 3; d++)
        #pragma unroll
        for (int j = 0; j < 2; j++)
            bv[d][j] = *(const bf16x8*)(bptr[j] + d * 64);

    // ---- stage A half 0 (kk = wid): 4 chunks of 1 KB per wave ----
    // chunk c = wid*4 + cc -> kk = wid, m = cc; staging lane writes 16B:
    // frag-row lane>>2, k-slot lane&3.
    int asrow = lane >> 2, askb = (lane & 3) * 16;
    #pragma unroll
    for (int cc = 0; cc < 4; ++cc) {
        GLOAD_LDS16(Ab + (size_t)(rowbase + cc * 16 + asrow) * 1024 + wid * 64 + askb,
                    (char*)As[0] + (wid * 4 + cc) * 1024);
    }
    __syncthreads();                                    // half-0 staged

    // issue half-1 staging (kk = 8 + wid); lands under half-0 compute
    #pragma unroll
    for (int cc = 0; cc < 4; ++cc) {
        GLOAD_LDS16(Ab + (size_t)(rowbase + cc * 16 + asrow) * 1024 + (8 + wid) * 64 + askb,
                    (char*)As[1] + (wid * 4 + cc) * 1024);
    }

    float tn = tnew[0];
    int albase = fr * 64 + rgrp * 16;          // reader offset within a frag

    f32x4 acc[4][2];                           // [m][j]
    #pragma unroll
    for (int m = 0; m < 4; m++)
        #pragma unroll
        for (int j = 0; j < 2; j++)
            acc[m][j] = (f32x4){0.f, 0.f, 0.f, 0.f};

    bf16x8 af[2][4];
    #pragma unroll
    for (int m = 0; m < 4; m++)
        af[0][m] = *(const bf16x8*)((const char*)As[0] + m * 1024 + albase);

    // ---- half 0: kk = 0..7 ----
    #pragma unroll
    for (int kk = 0; kk < 8; ++kk) {
        int cur = kk & 1;
        if (kk < 7) {
            #pragma unroll
            for (int m = 0; m < 4; m++)
                af[cur ^ 1][m] = *(const bf16x8*)((const char*)As[0]
                                 + ((kk + 1) * 4 + m) * 1024 + albase);
        }
        __builtin_amdgcn_s_setprio(1);
        #pragma unroll
        for (int m = 0; m < 4; m++)
            #pragma unroll
            for (int j = 0; j < 2; j++)
                acc[m][j] = __builtin_amdgcn_mfma_f32_16x16x32_bf16(
                                af[cur][m], bv[kk % 3][j], acc[m][j], 0, 0, 0);
        __builtin_amdgcn_s_setprio(0);
        {   // prefetch B for kk+3
            #pragma unroll
            for (int j = 0; j < 2; j++)
                bv[kk % 3][j] = *(const bf16x8*)(bptr[j] + (kk + 3) * 64);
        }
    }
    __syncthreads();                                    // half-1 staged

    #pragma unroll
    for (int m = 0; m < 4; m++)
        af[0][m] = *(const bf16x8*)((const char*)As[1] + m * 1024 + albase);

    // ---- half 1: kk = 8..15 ----
    #pragma unroll
    for (int kk = 8; kk < 16; ++kk) {
        int lk = kk - 8;
        int cur = lk & 1;
        if (lk < 7) {
            #pragma unroll
            for (int m = 0; m < 4; m++)
                af[cur ^ 1][m] = *(const bf16x8*)((const char*)As[1]
                                 + ((lk + 1) * 4 + m) * 1024 + albase);
        }
        __builtin_amdgcn_s_setprio(1);
        #pragma unroll
        for (int m = 0; m < 4; m++)
            #pragma unroll
            for (int j = 0; j < 2; j++)
                acc[m][j] = __builtin_amdgcn_mfma_f32_16x16x32_bf16(
                                af[cur][m], bv[kk % 3][j], acc[m][j], 0, 0, 0);
        __builtin_amdgcn_s_setprio(0);
        if (kk < 13) {
            #pragma unroll
            for (int j = 0; j < 2; j++)
                bv[kk % 3][j] = *(const bf16x8*)(bptr[j] + (kk + 3) * 64);
        }
    }

    // ---- epilogue: transform in place, then row (max, sumexp) ----
    // C/D layout: col = cb + j*16 + fr, row = m*16 + rgrp*4 + reg.
    #pragma unroll
    for (int m = 0; m < 4; m++) {
        #pragma unroll
        for (int reg = 0; reg < 4; reg++) {
            int rl = m * 16 + rgrp * 4 + reg;
            int tr = tgt_s[rl];
            float cm = ctm_s[rl];
            float ft = ftl_s[rl];
            #pragma unroll
            for (int j = 0; j < 2; j++) {
                int col = cb + j * 16 + fr;
                float c = acc[m][j][reg];
                c = fminf(fmaxf(c, -1.0f + EPS_F), 1.0f - EPS_F);
                float v = (c > cm) ? c * (tn + c) : c;
                v *= SCALE_F;
                v = (col == tr) ? ft * SCALE_F : v;
                v = (col < C_CLS) ? v : -3.0e38f;
                acc[m][j][reg] = v;
            }
        }
    }
    #pragma unroll
    for (int m = 0; m < 4; m++) {
        #pragma unroll
        for (int reg = 0; reg < 4; reg++) {
            float mx = fmaxf(acc[m][0][reg], acc[m][1][reg]);
            #pragma unroll
            for (int msk = 1; msk < 16; msk <<= 1) mx = fmaxf(mx, __shfl_xor(mx, msk));
            float sm = __expf(acc[m][0][reg] - mx) + __expf(acc[m][1][reg] - mx);
            #pragma unroll
            for (int msk = 1; msk < 16; msk <<= 1) sm += __shfl_xor(sm, msk);
            if (fr == 0) {
                int rl = m * 16 + rgrp * 4 + reg;
                redM[wid][rl] = mx;
                redS[wid][rl] = sm;
            }
        }
    }
    __syncthreads();
    if (tid < 64) {
        float M = redM[0][tid];
        #pragma unroll
        for (int wv = 1; wv < 8; wv++) M = fmaxf(M, redM[wv][tid]);
        float S = 0.0f;
        #pragma unroll
        for (int wv = 0; wv < 8; wv++)
            S += redS[wv][tid] * __expf(redM[wv][tid] - M);
        size_t odx = (size_t)(rowbase + tid) * NG + ng;
        pmax[odx] = M;
        psum[odx] = S;
    }
}

// ---------------------------------------------------------------------------
// K4 fallback (round-2 version): f32 W load + on-the-fly normalize/convert.
// grid NB*4 x 256, partials [512][NB]
// ---------------------------------------------------------------------------
__global__ __launch_bounds__(256) void k_gemm_epi(
        const unsigned short* __restrict__ xn,
        const float* __restrict__ w,
        const float* __restrict__ wnorm,
        const int* __restrict__ target,
        const float* __restrict__ ctm,
        const float* __restrict__ ftl,
        const float* __restrict__ tnew,
        float* __restrict__ pmax, float* __restrict__ psum) {
    __shared__ unsigned short As[128 * 32];
    __shared__ unsigned short Bs[128 * 32];
    __shared__ int   tgt_s[128];
    __shared__ float ctm_s[128];
    __shared__ float ftl_s[128];
    __shared__ float redM[2][128];
    __shared__ float redS[2][128];

    int bx = blockIdx.x;
    int nb = bx >> 2, mb = bx & 3;
    int rowbase = mb * 128, colbase = nb * 128;
    int tid = threadIdx.x;
    int lane = tid & 63, wid = tid >> 6;
    int wm = wid >> 1, wn = wid & 1;

    if (tid < 128) {
        int rg = rowbase + tid;
        tgt_s[tid] = target[rg];
        ctm_s[tid] = ctm[rg];
        ftl_s[tid] = ftl[rg];
    }
    float tn = tnew[0];

    int srow = tid >> 1;
    int skq  = (tid & 1) * 16;
    int cg = colbase + srow;
    float wscale = 0.0f;
    if (cg < C_CLS) wscale = 1.0f / wnorm[cg];

    f32x4 acc[4][4];
    #pragma unroll
    for (int m = 0; m < 4; m++)
        #pragma unroll
        for (int n = 0; n < 4; n++)
            acc[m][n] = (f32x4){0.f, 0.f, 0.f, 0.f};

    for (int kt = 0; kt < D_DIM / 32; ++kt) {
        int k0 = kt * 32;
        __syncthreads();
        {
            const uint4* src = (const uint4*)(xn + (rowbase + srow) * D_DIM + k0 + skq);
            uint4 a0 = src[0], a1 = src[1];
            *(uint4*)(&As[srow * 32 + skq])     = a0;
            *(uint4*)(&As[srow * 32 + skq + 8]) = a1;
        }
        {
            union { unsigned short h[16]; uint4 q[2]; } pk;
            if (cg < C_CLS) {
                const float4* src = (const float4*)(w + (size_t)cg * D_DIM + k0 + skq);
                #pragma unroll
                for (int q = 0; q < 4; q++) {
                    float4 v = src[q];
                    pk.h[q*4+0] = f2bf(v.x * wscale);
                    pk.h[q*4+1] = f2bf(v.y * wscale);
                    pk.h[q*4+2] = f2bf(v.z * wscale);
                    pk.h[q*4+3] = f2bf(v.w * wscale);
                }
            } else {
                #pragma unroll
                for (int j = 0; j < 16; j++) pk.h[j] = 0;
            }
            *(uint4*)(&Bs[srow * 32 + skq])     = pk.q[0];
            *(uint4*)(&Bs[srow * 32 + skq + 8]) = pk.q[1];
        }
        __syncthreads();
        int fr = lane & 15, kg = (lane >> 4) * 8;
        bf16x8 af[4], bfr[4];
        #pragma unroll
        for (int m = 0; m < 4; m++)
            af[m] = *(const bf16x8*)(&As[(wm * 64 + m * 16 + fr) * 32 + kg]);
        #pragma unroll
        for (int n = 0; n < 4; n++)
            bfr[n] = *(const bf16x8*)(&Bs[(wn * 64 + n * 16 + fr) * 32 + kg]);
        #pragma unroll
        for (int m = 0; m < 4; m++)
            #pragma unroll
            for (int n = 0; n < 4; n++)
                acc[m][n] = __builtin_amdgcn_mfma_f32_16x16x32_bf16(af[m], bfr[n], acc[m][n], 0, 0, 0);
    }

    int cgrp = lane & 15, rgrp = lane >> 4;
    #pragma unroll
    for (int m = 0; m < 4; m++) {
        #pragma unroll
        for (int reg = 0; reg < 4; reg++) {
            int rl = wm * 64 + m * 16 + rgrp * 4 + reg;
            int tr = tgt_s[rl];
            float cm = ctm_s[rl];
            float vv[4];
            bool valid[4];
            #pragma unroll
            for (int n = 0; n < 4; n++) {
                int cl = wn * 64 + n * 16 + cgrp;
                int cgl = colbase + cl;
                float c = acc[m][n][reg];
                c = fminf(fmaxf(c, -1.0f + EPS_F), 1.0f - EPS_F);
                float v;
                if (cgl >= C_CLS)      { v = -3.0e38f; valid[n] = false; }
                else if (cgl == tr)    { v = ftl_s[rl] * SCALE_F; valid[n] = true; }
                else {
                    v = (c > cm) ? c * (tn + c) : c;
                    v *= SCALE_F;
                    valid[n] = true;
                }
                vv[n] = v;
            }
            float mx = fmaxf(fmaxf(vv[0], vv[1]), fmaxf(vv[2], vv[3]));
            #pragma unroll
            for (int msk = 1; msk < 16; msk <<= 1) mx = fmaxf(mx, __shfl_xor(mx, msk));
            float sm = 0.0f;
            #pragma unroll
            for (int n = 0; n < 4; n++) sm += valid[n] ? __expf(vv[n] - mx) : 0.0f;
            #pragma unroll
            for (int msk = 1; msk < 16; msk <<= 1) sm += __shfl_xor(sm, msk);
            if (cgrp == 0) { redM[wn][rl] = mx; redS[wn][rl] = sm; }
        }
    }
    __syncthreads();
    if (tid < 128) {
        float m0 = redM[0][tid], s0 = redS[0][tid];
        float m1 = redM[1][tid], s1 = redS[1][tid];
        float M = fmaxf(m0, m1);
        float S = s0 * __expf(m0 - M) + s1 * __expf(m1 - M);
        size_t idx = (size_t)(rowbase + tid) * NB + nb;
        pmax[idx] = M;
        psum[idx] = S;
    }
}

// K5: per-row logsumexp over nbcnt partials -> loss_i.  grid 512 x 256
__global__ void k_rowlse(const float* __restrict__ pmax, const float* __restrict__ psum,
                         const float* __restrict__ ftl, float* __restrict__ lossi,
                         int nbcnt) {
    int row = blockIdx.x, tid = threadIdx.x;
    float M = -3.0e38f, S = 0.0f;
    for (int nb = tid; nb < nbcnt; nb += 256) {
        float m = pmax[(size_t)row * nbcnt + nb];
        float s = psum[(size_t)row * nbcnt + nb];
        float nm = fmaxf(M, m);
        S = S * __expf(M - nm) + s * __expf(m - nm);
        M = nm;
    }
    __shared__ float sM[256], sS[256];
    sM[tid] = M; sS[tid] = S;
    __syncthreads();
    for (int off = 128; off > 0; off >>= 1) {
        if (tid < off) {
            float m2 = sM[tid + off], s2 = sS[tid + off];
            float nm = fmaxf(sM[tid], m2);
            sS[tid] = sS[tid] * __expf(sM[tid] - nm) + s2 * __expf(m2 - nm);
            sM[tid] = nm;
        }
        __syncthreads();
    }
    if (tid == 0) lossi[row] = logf(sS[0]) + sM[0] - SCALE_F * ftl[row];
}

// K6: loss = mean(loss_i).  1 x 512
__global__ void k_final(const float* __restrict__ lossi, float* __restrict__ out) {
    __shared__ float s[512];
    int tid = threadIdx.x;
    s[tid] = lossi[tid];
    __syncthreads();
    for (int off = 256; off > 0; off >>= 1) {
        if (tid < off) s[tid] += s[tid + off];
        __syncthreads();
    }
    if (tid == 0) out[0] = s[0] / 512.0f;
}

extern "C" void kernel_launch(void* const* d_in, const int* in_sizes, int n_in,
                              void* d_out, int out_size, void* d_ws, size_t ws_size,
                              hipStream_t stream) {
    const float* x      = (const float*)d_in[0];
    const float* w      = (const float*)d_in[1];
    const float* t      = (const float*)d_in[2];
    const int*   target = (const int*)d_in[3];

    char* ws = (char*)d_ws;
    unsigned short* xn  = (unsigned short*)(ws + XN_OFF);
    float* xnorm = (float*)(ws + XNORM_OFF);
    float* wnorm = (float*)(ws + WNORM_OFF);
    float* tl    = (float*)(ws + TL_OFF);
    float* ctm   = (float*)(ws + CTM_OFF);
    float* ftl   = (float*)(ws + FTL_OFF);
    float* tnew  = (float*)(ws + TNEW_OFF);
    float* pmax  = (float*)(ws + PMAX_OFF);
    float* psum  = (float*)(ws + PSUM_OFF);
    float* lossi = (float*)(ws + LOSSI_OFF);
    unsigned short* wnb = (unsigned short*)(ws + WNBF_OFF);
    float* out   = (float*)d_out;

    bool fast = (ws_size >= WS_NEED_FAST);

    k_xnorm<<<dim3(N_ROWS), dim3(64), 0, stream>>>(x, xn, xnorm);
    if (fast) {
        k_wnorm_bf16<<<dim3(C_PAD / 4), dim3(256), 0, stream>>>(w, wnorm, wnb);
    } else {
        k_wnorm<<<dim3(C_CLS / 4), dim3(256), 0, stream>>>(w, wnorm);
    }
    k_tlogit<<<dim3(N_ROWS), dim3(64), 0, stream>>>(x, w, xnorm, wnorm, target, tl, ctm, ftl);
    k_tnew<<<dim3(1), dim3(512), 0, stream>>>(tl, t, tnew);
    if (fast) {
        k_gemm_stream<<<dim3(8 * NG), dim3(512), 0, stream>>>(xn, wnb, target, ctm, ftl, tnew, pmax, psum);
        k_rowlse<<<dim3(N_ROWS), dim3(256), 0, stream>>>(pmax, psum, ftl, lossi, NG);
    } else {
        k_gemm_epi<<<dim3(NB * 4), dim3(256), 0, stream>>>(xn, w, wnorm, target, ctm, ftl, tnew, pmax, psum);
        k_rowlse<<<dim3(N_ROWS), dim3(256), 0, stream>>>(pmax, psum, ftl, lossi, NB);
    }
    k_final<<<dim3(1), dim3(512), 0, stream>>>(lossi, out);
}

// Round 9
// 156.680 us; speedup vs baseline: 1.5001x; 1.1514x over previous
//
#include <hip/hip_runtime.h>
#include <hip/hip_bf16.h>
#include <stdint.h>

#define N_ROWS 512
#define D_DIM  512
#define C_CLS  100000
#define C_PAD  100096           // 391*256

#define SCALE_F    64.0f
#define EPS_F      1e-7f
#define COS_M_F    0.8775825618903728f
#define SIN_M_F    0.4794255386042030f
#define THRESH_F  -0.8775825618903728f
#define MM_F       0.2397127693021015f
#define FIXMAX_F   65.0f        // fixed softmax max: all logits <= 64*1.01 < 65

#define NB 782          // fallback col-blocks of 128
#define NG 391          // fast-path col-groups of 256

// ---- ws layout (bytes) ----
#define XN_OFF     0                          // bf16 bits [512][512]
#define XNORM_OFF  (XN_OFF + 512*512*2)       // f32 [512]
#define WNORM_OFF  (XNORM_OFF + 2048)         // f32 [100096]
#define TL_OFF     (WNORM_OFF + 100096*4)     // f32 [512]
#define CTM_OFF    (TL_OFF + 2048)            // f32 [512]
#define FTL_OFF    (CTM_OFF + 2048)           // f32 [512]
#define TNEW_OFF   (FTL_OFF + 2048)           // f32 [1] (padded)
#define PMAX_OFF   (TNEW_OFF + 256)           // f32 [512][NB] (fallback only)
#define PSUM_OFF   (PMAX_OFF + 512*NB*4)      // f32 [512][NB] (>= [512][NG])
#define LOSSI_OFF  (PSUM_OFF + 512*NB*4)      // f32 [512]
#define WNBF_OFF   (LOSSI_OFF + 2048)         // bf16 bits [100096][512] (fast path)
#define WS_NEED_FAST ((size_t)WNBF_OFF + (size_t)C_PAD*512*2)

typedef __attribute__((ext_vector_type(8))) short bf16x8;
typedef __attribute__((ext_vector_type(4))) float f32x4;

#define GLOAD_LDS16(gp, lp) \
    __builtin_amdgcn_global_load_lds((const __attribute__((address_space(1))) void*)(gp), \
                                     (__attribute__((address_space(3))) void*)(lp), 16, 0, 0)

__device__ inline unsigned short f2bf(float f) {
    union { float f; unsigned int u; } a; a.f = f;
    unsigned int r = (a.u + 0x7FFFu + ((a.u >> 16) & 1u)) >> 16;
    return (unsigned short)r;
}

__device__ inline float wave_sum64(float v) {
    #pragma unroll
    for (int m = 1; m < 64; m <<= 1) v += __shfl_xor(v, m);
    return v;
}

// K1: x row norms + xn bf16.  grid 512 x 64
__global__ void k_xnorm(const float* __restrict__ x,
                        unsigned short* __restrict__ xn,
                        float* __restrict__ xnorm) {
    int row = blockIdx.x;
    int lane = threadIdx.x;
    const float* xr = x + row * D_DIM + lane * 8;
    float4 v0 = *(const float4*)(xr);
    float4 v1 = *(const float4*)(xr + 4);
    float s = v0.x*v0.x + v0.y*v0.y + v0.z*v0.z + v0.w*v0.w
            + v1.x*v1.x + v1.y*v1.y + v1.z*v1.z + v1.w*v1.w;
    s = wave_sum64(s);
    float nrm = sqrtf(s);
    if (lane == 0) xnorm[row] = nrm;
    float inv = 1.0f / nrm;
    union { unsigned short h[8]; uint4 q; } u;
    u.h[0]=f2bf(v0.x*inv); u.h[1]=f2bf(v0.y*inv); u.h[2]=f2bf(v0.z*inv); u.h[3]=f2bf(v0.w*inv);
    u.h[4]=f2bf(v1.x*inv); u.h[5]=f2bf(v1.y*inv); u.h[6]=f2bf(v1.z*inv); u.h[7]=f2bf(v1.w*inv);
    *(uint4*)(xn + row * D_DIM + lane * 8) = u.q;
}

// K2 (fast): weight row norms + normalized bf16 W (pad rows zeroed).
// NON-TEMPORAL w reads: keep the fresh wnb resident in L3 for the GEMM.
// grid 25024 x 256 (wave per row)
__global__ void k_wnorm_bf16(const float* __restrict__ w, float* __restrict__ wnorm,
                             unsigned short* __restrict__ wnb) {
    int row = blockIdx.x * 4 + (threadIdx.x >> 6);
    int lane = threadIdx.x & 63;
    if (row < C_CLS) {
        const float* wr = w + (size_t)row * D_DIM + lane * 8;
        f32x4 v0 = __builtin_nontemporal_load((const f32x4*)(wr));
        f32x4 v1 = __builtin_nontemporal_load((const f32x4*)(wr + 4));
        float s = v0.x*v0.x + v0.y*v0.y + v0.z*v0.z + v0.w*v0.w
                + v1.x*v1.x + v1.y*v1.y + v1.z*v1.z + v1.w*v1.w;
        s = wave_sum64(s);
        float nrm = sqrtf(s);
        if (lane == 0) wnorm[row] = nrm;
        float inv = 1.0f / nrm;
        union { unsigned short h[8]; uint4 q; } u;
        u.h[0]=f2bf(v0.x*inv); u.h[1]=f2bf(v0.y*inv); u.h[2]=f2bf(v0.z*inv); u.h[3]=f2bf(v0.w*inv);
        u.h[4]=f2bf(v1.x*inv); u.h[5]=f2bf(v1.y*inv); u.h[6]=f2bf(v1.z*inv); u.h[7]=f2bf(v1.w*inv);
        *(uint4*)(wnb + (size_t)row * D_DIM + lane * 8) = u.q;
    } else {
        uint4 z = {0u, 0u, 0u, 0u};
        *(uint4*)(wnb + (size_t)row * D_DIM + lane * 8) = z;
    }
}

// K2 (fallback): weight row norms only.  grid 25000 x 256
__global__ void k_wnorm(const float* __restrict__ w, float* __restrict__ wnorm) {
    int row = blockIdx.x * 4 + (threadIdx.x >> 6);
    int lane = threadIdx.x & 63;
    const float* wr = w + (size_t)row * D_DIM + lane * 8;
    float4 v0 = *(const float4*)(wr);
    float4 v1 = *(const float4*)(wr + 4);
    float s = v0.x*v0.x + v0.y*v0.y + v0.z*v0.z + v0.w*v0.w
            + v1.x*v1.x + v1.y*v1.y + v1.z*v1.z + v1.w*v1.w;
    s = wave_sum64(s);
    if (lane == 0) wnorm[row] = sqrtf(s);
}

// K3: per-row target logit + margin terms (exact f32).  grid 512 x 64
__global__ void k_tlogit(const float* __restrict__ x, const float* __restrict__ w,
                         const float* __restrict__ xnorm, const float* __restrict__ wnorm,
                         const int* __restrict__ target,
                         float* __restrict__ tl, float* __restrict__ ctm,
                         float* __restrict__ ftl) {
    int row = blockIdx.x;
    int lane = threadIdx.x;
    int tgt = target[row];
    const float* xr = x + row * D_DIM + lane * 8;
    const float* wr = w + (size_t)tgt * D_DIM + lane * 8;
    float4 a0 = *(const float4*)(xr),     a1 = *(const float4*)(xr + 4);
    float4 b0 = *(const float4*)(wr),     b1 = *(const float4*)(wr + 4);
    float s = a0.x*b0.x + a0.y*b0.y + a0.z*b0.z + a0.w*b0.w
            + a1.x*b1.x + a1.y*b1.y + a1.z*b1.z + a1.w*b1.w;
    s = wave_sum64(s);
    if (lane == 0) {
        float c = s / (xnorm[row] * wnorm[tgt]);
        c = fminf(fmaxf(c, -1.0f + EPS_F), 1.0f - EPS_F);
        float sn = sqrtf(fmaxf(1.0f - c * c, 0.0f));
        float cm = c * COS_M_F - sn * SIN_M_F;
        tl[row]  = c;
        ctm[row] = cm;
        ftl[row] = (c > THRESH_F) ? cm : (c - MM_F);
    }
}

// K3b: t_new = mean(tl)*0.01 + 0.99*t.  1 x 512
__global__ void k_tnew(const float* __restrict__ tl, const float* __restrict__ t,
                       float* __restrict__ tnew) {
    __shared__ float s[512];
    int tid = threadIdx.x;
    s[tid] = tl[tid];
    __syncthreads();
    for (int off = 256; off > 0; off >>= 1) {
        if (tid < off) s[tid] += s[tid + off];
        __syncthreads();
    }
    if (tid == 0) tnew[0] = (s[0] / 512.0f) * 0.01f + 0.99f * t[0];
}

// ---------------------------------------------------------------------------
// K4 fast: barrier-free streaming GEMM, depth-6 B ring + fixed-max epilogue.
//  - block = 8 waves (512 thr), 64 A-rows, 256 classes; wave owns 32 classes.
//  - A staged ONCE (64KB, frag-major [kk][m][1KB], conflict-free ds_read);
//    ONE pre-compute barrier.
//  - B streams global->VGPR with depth-6 ring (reissue before MFMA cluster).
//  - epilogue: fixed softmax max (=65) -> exp+sum only, no max reduce.
// grid 3128 x 512
// ---------------------------------------------------------------------------
__global__ __launch_bounds__(512, 4) void k_gemm_stream(
        const unsigned short* __restrict__ xn,    // bf16 [512][512]
        const unsigned short* __restrict__ wnb,   // bf16 [100096][512], normalized
        const int* __restrict__ target,
        const float* __restrict__ ctm,
        const float* __restrict__ ftl,
        const float* __restrict__ tnew,
        float* __restrict__ psum) {
    __shared__ unsigned short As[16 * 4 * 512];   // 64 KB, [kk][m][1KB frag]
    __shared__ int   tgt_s[64];
    __shared__ float ctm_s[64];
    __shared__ float ftl_s[64];
    __shared__ float redS[8][64];

    // XCD remap: 3128 = 8*391; all 8 mb-siblings of an ng share one XCD.
    int bx = blockIdx.x;
    int logical = (bx & 7) * 391 + (bx >> 3);
    int ng = logical >> 3, mb = logical & 7;
    int rowbase = mb * 64;

    int tid = threadIdx.x;
    int lane = tid & 63, wid = tid >> 6;       // wid 0..7
    int fr = lane & 15, rgrp = lane >> 4;
    int cb = ng * 256 + wid * 32;              // this wave's first class (32)

    if (tid < 64) {
        int rg = rowbase + tid;
        tgt_s[tid] = target[rg];
        ctm_s[tid] = ctm[rg];
        ftl_s[tid] = ftl[rg];
    }

    const char* Ab = (const char*)xn;     // row stride 1024 B
    const char* Bb = (const char*)wnb;    // row stride 1024 B

    // ---- B lane base pointers (j-tile j): row = cb + j*16 + fr ----
    const char* bptr[2];
    #pragma unroll
    for (int j = 0; j < 2; j++)
        bptr[j] = Bb + (size_t)(cb + j * 16 + fr) * 1024 + rgrp * 16;

    // ---- B preloads kk=0..5 (depth-6 ring) ----
    bf16x8 bv[6][2];
    #pragma unroll
    for (int d = 0; d < 6; d++)
        #pragma unroll
        for (int j = 0; j < 2; j++)
            bv[d][j] = *(const bf16x8*)(bptr[j] + d * 64);

    // ---- stage full A (64 chunks of 1 KB, 8 per wave): c = kk*4+m ----
    // staging lane writes 16B: frag-row lane>>2, k-slot lane&3.
    int asrow = lane >> 2, askb = (lane & 3) * 16;
    #pragma unroll
    for (int cc = 0; cc < 8; ++cc) {
        int c = wid * 8 + cc;
        int kk = c >> 2, m = c & 3;
        GLOAD_LDS16(Ab + (size_t)(rowbase + m * 16 + asrow) * 1024 + kk * 64 + askb,
                    (char*)As + c * 1024);
    }
    __syncthreads();                           // the ONLY pre-compute barrier

    float tn = tnew[0];
    int albase = fr * 64 + rgrp * 16;          // reader offset within a frag

    f32x4 acc[4][2];                           // [m][j]
    #pragma unroll
    for (int m = 0; m < 4; m++)
        #pragma unroll
        for (int j = 0; j < 2; j++)
            acc[m][j] = (f32x4){0.f, 0.f, 0.f, 0.f};

    bf16x8 af[2][4];
    #pragma unroll
    for (int m = 0; m < 4; m++)
        af[0][m] = *(const bf16x8*)((const char*)As + m * 1024 + albase);

    #pragma unroll
    for (int kk = 0; kk < 16; ++kk) {
        int cur = kk & 1;
        if (kk < 15) {
            #pragma unroll
            for (int m = 0; m < 4; m++)
                af[cur ^ 1][m] = *(const bf16x8*)((const char*)As
                                 + ((kk + 1) * 4 + m) * 1024 + albase);
        }
        if (kk < 10) {   // reissue ring slot for kk+6, BEFORE the MFMA cluster
            #pragma unroll
            for (int j = 0; j < 2; j++)
                bv[(kk + 6) % 6][j] = *(const bf16x8*)(bptr[j] + (kk + 6) * 64);
        }
        __builtin_amdgcn_s_setprio(1);
        #pragma unroll
        for (int m = 0; m < 4; m++)
            #pragma unroll
            for (int j = 0; j < 2; j++)
                acc[m][j] = __builtin_amdgcn_mfma_f32_16x16x32_bf16(
                                af[cur][m], bv[kk % 6][j], acc[m][j], 0, 0, 0);
        __builtin_amdgcn_s_setprio(0);
    }

    // ---- epilogue: fixed-max (65) transform + exp + row sum ----
    // C/D layout: col = cb + j*16 + fr, row = m*16 + rgrp*4 + reg.
    #pragma unroll
    for (int m = 0; m < 4; m++) {
        #pragma unroll
        for (int reg = 0; reg < 4; reg++) {
            int rl = m * 16 + rgrp * 4 + reg;
            int tr = tgt_s[rl];
            float cm = ctm_s[rl];
            float ft = ftl_s[rl];
            float sm = 0.0f;
            #pragma unroll
            for (int j = 0; j < 2; j++) {
                int col = cb + j * 16 + fr;
                float c = acc[m][j][reg];
                c = fminf(fmaxf(c, -1.0f + EPS_F), 1.0f - EPS_F);
                float v = (c > cm) ? c * (tn + c) : c;
                v *= SCALE_F;
                v = (col == tr) ? ft * SCALE_F : v;
                v = (col < C_CLS) ? v : -3.0e38f;   // exp -> 0
                sm += __expf(v - FIXMAX_F);
            }
            #pragma unroll
            for (int msk = 1; msk < 16; msk <<= 1) sm += __shfl_xor(sm, msk);
            if (fr == 0) redS[wid][rl] = sm;
        }
    }
    __syncthreads();
    if (tid < 64) {
        float S = 0.0f;
        #pragma unroll
        for (int wv = 0; wv < 8; wv++) S += redS[wv][tid];
        psum[(size_t)(rowbase + tid) * NG + ng] = S;
    }
}

// K5 (fast): per-row sum over NG partials (fixed max) -> loss_i.  grid 512 x 256
__global__ void k_rowlse_fix(const float* __restrict__ psum,
                             const float* __restrict__ ftl,
                             float* __restrict__ lossi) {
    int row = blockIdx.x, tid = threadIdx.x;
    float S = 0.0f;
    for (int nb = tid; nb < NG; nb += 256) S += psum[(size_t)row * NG + nb];
    __shared__ float sS[256];
    sS[tid] = S;
    __syncthreads();
    for (int off = 128; off > 0; off >>= 1) {
        if (tid < off) sS[tid] += sS[tid + off];
        __syncthreads();
    }
    if (tid == 0) lossi[row] = logf(sS[0]) + FIXMAX_F - SCALE_F * ftl[row];
}

// ---------------------------------------------------------------------------
// K4 fallback (round-2 version): f32 W load + on-the-fly normalize/convert.
// grid NB*4 x 256, partials [512][NB]
// ---------------------------------------------------------------------------
__global__ __launch_bounds__(256) void k_gemm_epi(
        const unsigned short* __restrict__ xn,
        const float* __restrict__ w,
        const float* __restrict__ wnorm,
        const int* __restrict__ target,
        const float* __restrict__ ctm,
        const float* __restrict__ ftl,
        const float* __restrict__ tnew,
        float* __restrict__ pmax, float* __restrict__ psum) {
    __shared__ unsigned short As[128 * 32];
    __shared__ unsigned short Bs[128 * 32];
    __shared__ int   tgt_s[128];
    __shared__ float ctm_s[128];
    __shared__ float ftl_s[128];
    __shared__ float redM[2][128];
    __shared__ float redS[2][128];

    int bx = blockIdx.x;
    int nb = bx >> 2, mb = bx & 3;
    int rowbase = mb * 128, colbase = nb * 128;
    int tid = threadIdx.x;
    int lane = tid & 63, wid = tid >> 6;
    int wm = wid >> 1, wn = wid & 1;

    if (tid < 128) {
        int rg = rowbase + tid;
        tgt_s[tid] = target[rg];
        ctm_s[tid] = ctm[rg];
        ftl_s[tid] = ftl[rg];
    }
    float tn = tnew[0];

    int srow = tid >> 1;
    int skq  = (tid & 1) * 16;
    int cg = colbase + srow;
    float wscale = 0.0f;
    if (cg < C_CLS) wscale = 1.0f / wnorm[cg];

    f32x4 acc[4][4];
    #pragma unroll
    for (int m = 0; m < 4; m++)
        #pragma unroll
        for (int n = 0; n < 4; n++)
            acc[m][n] = (f32x4){0.f, 0.f, 0.f, 0.f};

    for (int kt = 0; kt < D_DIM / 32; ++kt) {
        int k0 = kt * 32;
        __syncthreads();
        {
            const uint4* src = (const uint4*)(xn + (rowbase + srow) * D_DIM + k0 + skq);
            uint4 a0 = src[0], a1 = src[1];
            *(uint4*)(&As[srow * 32 + skq])     = a0;
            *(uint4*)(&As[srow * 32 + skq + 8]) = a1;
        }
        {
            union { unsigned short h[16]; uint4 q[2]; } pk;
            if (cg < C_CLS) {
                const float4* src = (const float4*)(w + (size_t)cg * D_DIM + k0 + skq);
                #pragma unroll
                for (int q = 0; q < 4; q++) {
                    float4 v = src[q];
                    pk.h[q*4+0] = f2bf(v.x * wscale);
                    pk.h[q*4+1] = f2bf(v.y * wscale);
                    pk.h[q*4+2] = f2bf(v.z * wscale);
                    pk.h[q*4+3] = f2bf(v.w * wscale);
                }
            } else {
                #pragma unroll
                for (int j = 0; j < 16; j++) pk.h[j] = 0;
            }
            *(uint4*)(&Bs[srow * 32 + skq])     = pk.q[0];
            *(uint4*)(&Bs[srow * 32 + skq + 8]) = pk.q[1];
        }
        __syncthreads();
        int fr = lane & 15, kg = (lane >> 4) * 8;
        bf16x8 af[4], bfr[4];
        #pragma unroll
        for (int m = 0; m < 4; m++)
            af[m] = *(const bf16x8*)(&As[(wm * 64 + m * 16 + fr) * 32 + kg]);
        #pragma unroll
        for (int n = 0; n < 4; n++)
            bfr[n] = *(const bf16x8*)(&Bs[(wn * 64 + n * 16 + fr) * 32 + kg]);
        #pragma unroll
        for (int m = 0; m < 4; m++)
            #pragma unroll
            for (int n = 0; n < 4; n++)
                acc[m][n] = __builtin_amdgcn_mfma_f32_16x16x32_bf16(af[m], bfr[n], acc[m][n], 0, 0, 0);
    }

    int cgrp = lane & 15, rgrp = lane >> 4;
    #pragma unroll
    for (int m = 0; m < 4; m++) {
        #pragma unroll
        for (int reg = 0; reg < 4; reg++) {
            int rl = wm * 64 + m * 16 + rgrp * 4 + reg;
            int tr = tgt_s[rl];
            float cm = ctm_s[rl];
            float vv[4];
            bool valid[4];
            #pragma unroll
            for (int n = 0; n < 4; n++) {
                int cl = wn * 64 + n * 16 + cgrp;
                int cgl = colbase + cl;
                float c = acc[m][n][reg];
                c = fminf(fmaxf(c, -1.0f + EPS_F), 1.0f - EPS_F);
                float v;
                if (cgl >= C_CLS)      { v = -3.0e38f; valid[n] = false; }
                else if (cgl == tr)    { v = ftl_s[rl] * SCALE_F; valid[n] = true; }
                else {
                    v = (c > cm) ? c * (tn + c) : c;
                    v *= SCALE_F;
                    valid[n] = true;
                }
                vv[n] = v;
            }
            float mx = fmaxf(fmaxf(vv[0], vv[1]), fmaxf(vv[2], vv[3]));
            #pragma unroll
            for (int msk = 1; msk < 16; msk <<= 1) mx = fmaxf(mx, __shfl_xor(mx, msk));
            float sm = 0.0f;
            #pragma unroll
            for (int n = 0; n < 4; n++) sm += valid[n] ? __expf(vv[n] - mx) : 0.0f;
            #pragma unroll
            for (int msk = 1; msk < 16; msk <<= 1) sm += __shfl_xor(sm, msk);
            if (cgrp == 0) { redM[wn][rl] = mx; redS[wn][rl] = sm; }
        }
    }
    __syncthreads();
    if (tid < 128) {
        float m0 = redM[0][tid], s0 = redS[0][tid];
        float m1 = redM[1][tid], s1 = redS[1][tid];
        float M = fmaxf(m0, m1);
        float S = s0 * __expf(m0 - M) + s1 * __expf(m1 - M);
        size_t idx = (size_t)(rowbase + tid) * NB + nb;
        pmax[idx] = M;
        psum[idx] = S;
    }
}

// K5 (fallback): per-row logsumexp over NB partials -> loss_i.  grid 512 x 256
__global__ void k_rowlse(const float* __restrict__ pmax, const float* __restrict__ psum,
                         const float* __restrict__ ftl, float* __restrict__ lossi,
                         int nbcnt) {
    int row = blockIdx.x, tid = threadIdx.x;
    float M = -3.0e38f, S = 0.0f;
    for (int nb = tid; nb < nbcnt; nb += 256) {
        float m = pmax[(size_t)row * nbcnt + nb];
        float s = psum[(size_t)row * nbcnt + nb];
        float nm = fmaxf(M, m);
        S = S * __expf(M - nm) + s * __expf(m - nm);
        M = nm;
    }
    __shared__ float sM[256], sS[256];
    sM[tid] = M; sS[tid] = S;
    __syncthreads();
    for (int off = 128; off > 0; off >>= 1) {
        if (tid < off) {
            float m2 = sM[tid + off], s2 = sS[tid + off];
            float nm = fmaxf(sM[tid], m2);
            sS[tid] = sS[tid] * __expf(sM[tid] - nm) + s2 * __expf(m2 - nm);
            sM[tid] = nm;
        }
        __syncthreads();
    }
    if (tid == 0) lossi[row] = logf(sS[0]) + sM[0] - SCALE_F * ftl[row];
}

// K6: loss = mean(loss_i).  1 x 512
__global__ void k_final(const float* __restrict__ lossi, float* __restrict__ out) {
    __shared__ float s[512];
    int tid = threadIdx.x;
    s[tid] = lossi[tid];
    __syncthreads();
    for (int off = 256; off > 0; off >>= 1) {
        if (tid < off) s[tid] += s[tid + off];
        __syncthreads();
    }
    if (tid == 0) out[0] = s[0] / 512.0f;
}

extern "C" void kernel_launch(void* const* d_in, const int* in_sizes, int n_in,
                              void* d_out, int out_size, void* d_ws, size_t ws_size,
                              hipStream_t stream) {
    const float* x      = (const float*)d_in[0];
    const float* w      = (const float*)d_in[1];
    const float* t      = (const float*)d_in[2];
    const int*   target = (const int*)d_in[3];

    char* ws = (char*)d_ws;
    unsigned short* xn  = (unsigned short*)(ws + XN_OFF);
    float* xnorm = (float*)(ws + XNORM_OFF);
    float* wnorm = (float*)(ws + WNORM_OFF);
    float* tl    = (float*)(ws + TL_OFF);
    float* ctm   = (float*)(ws + CTM_OFF);
    float* ftl   = (float*)(ws + FTL_OFF);
    float* tnew  = (float*)(ws + TNEW_OFF);
    float* pmax  = (float*)(ws + PMAX_OFF);
    float* psum  = (float*)(ws + PSUM_OFF);
    float* lossi = (float*)(ws + LOSSI_OFF);
    unsigned short* wnb = (unsigned short*)(ws + WNBF_OFF);
    float* out   = (float*)d_out;

    bool fast = (ws_size >= WS_NEED_FAST);

    k_xnorm<<<dim3(N_ROWS), dim3(64), 0, stream>>>(x, xn, xnorm);
    if (fast) {
        k_wnorm_bf16<<<dim3(C_PAD / 4), dim3(256), 0, stream>>>(w, wnorm, wnb);
    } else {
        k_wnorm<<<dim3(C_CLS / 4), dim3(256), 0, stream>>>(w, wnorm);
    }
    k_tlogit<<<dim3(N_ROWS), dim3(64), 0, stream>>>(x, w, xnorm, wnorm, target, tl, ctm, ftl);
    k_tnew<<<dim3(1), dim3(512), 0, stream>>>(tl, t, tnew);
    if (fast) {
        k_gemm_stream<<<dim3(8 * NG), dim3(512), 0, stream>>>(xn, wnb, target, ctm, ftl, tnew, psum);
        k_rowlse_fix<<<dim3(N_ROWS), dim3(256), 0, stream>>>(psum, ftl, lossi);
    } else {
        k_gemm_epi<<<dim3(NB * 4), dim3(256), 0, stream>>>(xn, w, wnorm, target, ctm, ftl, tnew, pmax, psum);
        k_rowlse<<<dim3(N_ROWS), dim3(256), 0, stream>>>(pmax, psum, ftl, lossi, NB);
    }
    k_final<<<dim3(1), dim3(512), 0, stream>>>(lossi, out);
}